// Round 2
// baseline (474.312 us; speedup 1.0000x reference)
//
#include <hip/hip_runtime.h>
#include <hip/hip_bf16.h>

constexpr int B = 64, N = 512, F_IN = 256, D = 128, TOPK = 20, HID = 512;

// ---------------- K0: row norms of emb ----------------
__global__ void k_norm(const float* __restrict__ W, float* __restrict__ inv_norm) {
    int i = blockIdx.x, t = threadIdx.x;  // 128 threads
    float v = W[i * D + t];
    float s = v * v;
    #pragma unroll
    for (int o = 32; o > 0; o >>= 1) s += __shfl_down(s, o);
    __shared__ float red[2];
    if ((t & 63) == 0) red[t >> 6] = s;
    __syncthreads();
    if (t == 0) inv_norm[i] = 1.0f / sqrtf(red[0] + red[1]);
}

// ---------------- K1: cosine row + top-20 (tie: lower index) ----------------
__global__ void k_topk(const float* __restrict__ W, const float* __restrict__ inv_norm,
                       int* __restrict__ topk, float* __restrict__ out_idx) {
    __shared__ float wrow[D];
    __shared__ float cosr[N];
    __shared__ float rval[256];
    __shared__ int   ridx[256];
    int i = blockIdx.x, t = threadIdx.x;  // 256 threads
    if (t < D) wrow[t] = W[i * D + t];
    __syncthreads();
    float inv_i = inv_norm[i];
    for (int j = t; j < N; j += 256) {
        const float* wj = W + j * D;
        float dot = 0.f;
        #pragma unroll
        for (int k = 0; k < D; k += 4) {
            float4 a = *(const float4*)(wj + k);
            dot += wrow[k] * a.x + wrow[k + 1] * a.y + wrow[k + 2] * a.z + wrow[k + 3] * a.w;
        }
        cosr[j] = dot * inv_i * inv_norm[j];
    }
    __syncthreads();
    for (int k = 0; k < TOPK; ++k) {
        float bv = -INFINITY; int bi = 0;
        for (int j = t; j < N; j += 256) {
            float v = cosr[j];
            if (v > bv) { bv = v; bi = j; }   // j increasing: ties keep lower index
        }
        rval[t] = bv; ridx[t] = bi;
        __syncthreads();
        for (int s = 128; s > 0; s >>= 1) {
            if (t < s) {
                float ov = rval[t + s]; int oi = ridx[t + s];
                if (ov > rval[t] || (ov == rval[t] && oi < ridx[t])) { rval[t] = ov; ridx[t] = oi; }
            }
            __syncthreads();
        }
        if (t == 0) {
            int m = ridx[0];
            topk[i * TOPK + k] = m;
            out_idx[i * TOPK + k] = (float)m;
            cosr[m] = -INFINITY;
        }
        __syncthreads();
    }
}

// ---------------- emb passthrough output (f32) ----------------
__global__ void k_emb_out(const float* __restrict__ emb, float* __restrict__ o) {
    int k = blockIdx.x * 256 + threadIdx.x;   // 64 blocks x 256 = 16384 threads, 4 elems each
    for (; k < N * D; k += 64 * 256) o[k] = emb[k];
}

// ---------------- K2: xl = x @ lin_w^T  (x[b*N+n][f] = data[b][f][n]) ----------------
__global__ __launch_bounds__(256) void k_xl(const float* __restrict__ data,
                                            const float* __restrict__ lin_w,
                                            float* __restrict__ xl) {
    __shared__ float lx[32][32];   // [kk][c]
    __shared__ float lw[32][128];  // [kk][d]
    int n0 = blockIdx.x * 32, b = blockIdx.y, t = threadIdx.x;
    int cx = (t & 7) * 4, dx = (t >> 3) * 4;
    float acc[4][4] = {};
    for (int k0 = 0; k0 < F_IN; k0 += 32) {
        #pragma unroll
        for (int i = 0; i < 4; ++i) {
            int lin = t + i * 256, c = lin & 31, kk = lin >> 5;
            lx[kk][c] = data[(b * F_IN + k0 + kk) * N + n0 + c];
        }
        #pragma unroll
        for (int i = 0; i < 16; ++i) {
            int lin = t + i * 256, d = lin & 127, kk = lin >> 7;
            lw[kk][d] = lin_w[d * F_IN + k0 + kk];
        }
        __syncthreads();
        #pragma unroll
        for (int kk = 0; kk < 32; ++kk) {
            float4 a = *(const float4*)&lx[kk][cx];
            float4 w = *(const float4*)&lw[kk][dx];
            float av[4] = {a.x, a.y, a.z, a.w}, wv[4] = {w.x, w.y, w.z, w.w};
            #pragma unroll
            for (int jc = 0; jc < 4; ++jc)
                #pragma unroll
                for (int jd = 0; jd < 4; ++jd) acc[jc][jd] += av[jc] * wv[jd];
        }
        __syncthreads();
    }
    #pragma unroll
    for (int jc = 0; jc < 4; ++jc) {
        float4 v = {acc[jc][0], acc[jc][1], acc[jc][2], acc[jc][3]};
        *(float4*)&xl[(b * N + n0 + cx + jc) * D + dx] = v;
    }
}

// ---------------- K3: per-node attention scores ----------------
__global__ void k_scores(const float* __restrict__ xl, const float* __restrict__ emb,
                         const float* __restrict__ att_i, const float* __restrict__ att_j,
                         const float* __restrict__ att_em_i, const float* __restrict__ att_em_j,
                         float* __restrict__ s_i, float* __restrict__ s_j) {
    int n = blockIdx.x, b = blockIdx.y, t = threadIdx.x;  // 128 threads
    int v = b * N + n;
    float x = xl[v * D + t], e = emb[n * D + t];
    float si = x * att_i[t] + e * att_em_i[t];
    float sj = x * att_j[t] + e * att_em_j[t];
    #pragma unroll
    for (int o = 32; o > 0; o >>= 1) { si += __shfl_down(si, o); sj += __shfl_down(sj, o); }
    __shared__ float r[4];
    if ((t & 63) == 0) { r[(t >> 6) * 2] = si; r[(t >> 6) * 2 + 1] = sj; }
    __syncthreads();
    if (t == 0) { s_i[v] = r[0] + r[2]; s_j[v] = r[1] + r[3]; }
}

// ---------------- K4: softmax over 20 + aggregate + BN + ReLU + emb gate ----------------
__global__ void k_attn(const float* __restrict__ xl, const float* __restrict__ emb,
                       const int* __restrict__ topk, const float* __restrict__ s_i,
                       const float* __restrict__ s_j, const float* __restrict__ gnn_bias,
                       const float* __restrict__ bn_gamma, const float* __restrict__ bn_beta,
                       float* __restrict__ gcnemb) {
    __shared__ float a[TOPK];
    __shared__ int js[TOPK];
    int n = blockIdx.x, b = blockIdx.y, t = threadIdx.x;  // 128 threads
    int v = b * N + n;
    if (t < TOPK) {
        int j = topk[n * TOPK + t];
        js[t] = j;
        float al = s_i[v] + s_j[b * N + j];
        a[t] = al >= 0.f ? al : 0.2f * al;
    }
    __syncthreads();
    if (t == 0) {
        float m = -INFINITY;
        for (int k = 0; k < TOPK; ++k) m = fmaxf(m, a[k]);
        float s = 0.f;
        for (int k = 0; k < TOPK; ++k) { a[k] = expf(a[k] - m); s += a[k]; }
        float inv = 1.0f / s;
        for (int k = 0; k < TOPK; ++k) a[k] *= inv;
    }
    __syncthreads();
    float acc = 0.f;
    #pragma unroll 4
    for (int k = 0; k < TOPK; ++k) acc += a[k] * xl[(b * N + js[k]) * D + t];
    float h = (acc + gnn_bias[t]) * (bn_gamma[t] * (1.0f / sqrtf(1.0f + 1e-5f))) + bn_beta[t];
    h = fmaxf(h, 0.f);
    gcnemb[(b * N + n) * D + t] = h * emb[n * D + t];
}

// ---------------- K5: out1[b][d][h] = sum_n G[b][n][d] * w1[h][n] ----------------
__global__ __launch_bounds__(256) void k_gemm1(const float* __restrict__ G,
                                               const float* __restrict__ w1,
                                               float* __restrict__ out1) {
    __shared__ float la[32][64];  // [kk][dl]
    __shared__ float lb[32][64];  // [kk][hl]
    int h0 = blockIdx.x * 64, d0 = blockIdx.y * 64, b = blockIdx.z, t = threadIdx.x;
    int dxl = (t & 15) * 4, hxl = (t >> 4) * 4;
    float acc[4][4] = {};
    for (int k0 = 0; k0 < N; k0 += 32) {
        #pragma unroll
        for (int i = 0; i < 8; ++i) {
            int lin = t + i * 256, dl = lin & 63, kk = lin >> 6;
            la[kk][dl] = G[(b * N + k0 + kk) * D + d0 + dl];
            lb[kk][dl] = w1[(h0 + dl) * N + k0 + kk];
        }
        __syncthreads();
        #pragma unroll
        for (int kk = 0; kk < 32; ++kk) {
            float4 a = *(const float4*)&la[kk][dxl];
            float4 w = *(const float4*)&lb[kk][hxl];
            float av[4] = {a.x, a.y, a.z, a.w}, wv[4] = {w.x, w.y, w.z, w.w};
            #pragma unroll
            for (int jd = 0; jd < 4; ++jd)
                #pragma unroll
                for (int jh = 0; jh < 4; ++jh) acc[jd][jh] += av[jd] * wv[jh];
        }
        __syncthreads();
    }
    #pragma unroll
    for (int jd = 0; jd < 4; ++jd) {
        float4 v = {acc[jd][0], acc[jd][1], acc[jd][2], acc[jd][3]};
        *(float4*)&out1[b * D * HID + (d0 + dxl + jd) * HID + h0 + hxl] = v;
    }
}

// ---------------- K6: out = sigmoid(O1 @ w2^T + b2), f32 output ----------------
__global__ __launch_bounds__(256) void k_gemm2(const float* __restrict__ O1,
                                               const float* __restrict__ w2,
                                               const float* __restrict__ b2,
                                               float* __restrict__ out) {
    __shared__ float la[32][64];  // [kk][dl]
    __shared__ float lb[32][64];  // [kk][hl]
    int h0 = blockIdx.x * 64, d0 = blockIdx.y * 64, b = blockIdx.z, t = threadIdx.x;
    int dxl = (t & 15) * 4, hxl = (t >> 4) * 4;
    float acc[4][4] = {};
    for (int k0 = 0; k0 < HID; k0 += 32) {
        #pragma unroll
        for (int i = 0; i < 8; ++i) {
            int lin = t + i * 256, dl = lin & 63, kk = lin >> 6;
            la[kk][dl] = O1[b * D * HID + (d0 + dl) * HID + k0 + kk];
            lb[kk][dl] = w2[(h0 + dl) * HID + k0 + kk];
        }
        __syncthreads();
        #pragma unroll
        for (int kk = 0; kk < 32; ++kk) {
            float4 a = *(const float4*)&la[kk][dxl];
            float4 w = *(const float4*)&lb[kk][hxl];
            float av[4] = {a.x, a.y, a.z, a.w}, wv[4] = {w.x, w.y, w.z, w.w};
            #pragma unroll
            for (int jd = 0; jd < 4; ++jd)
                #pragma unroll
                for (int jh = 0; jh < 4; ++jh) acc[jd][jh] += av[jd] * wv[jh];
        }
        __syncthreads();
    }
    #pragma unroll
    for (int jd = 0; jd < 4; ++jd) {
        float4 v;
        v.x = 1.0f / (1.0f + expf(-(acc[jd][0] + b2[h0 + hxl + 0])));
        v.y = 1.0f / (1.0f + expf(-(acc[jd][1] + b2[h0 + hxl + 1])));
        v.z = 1.0f / (1.0f + expf(-(acc[jd][2] + b2[h0 + hxl + 2])));
        v.w = 1.0f / (1.0f + expf(-(acc[jd][3] + b2[h0 + hxl + 3])));
        *(float4*)&out[b * D * HID + (d0 + dxl + jd) * HID + h0 + hxl] = v;
    }
}

extern "C" void kernel_launch(void* const* d_in, const int* in_sizes, int n_in,
                              void* d_out, int out_size, void* d_ws, size_t ws_size,
                              hipStream_t stream) {
    const float* data     = (const float*)d_in[0];
    const float* emb      = (const float*)d_in[1];
    const float* lin_w    = (const float*)d_in[2];
    const float* att_i    = (const float*)d_in[3];
    const float* att_j    = (const float*)d_in[4];
    const float* att_em_i = (const float*)d_in[5];
    const float* att_em_j = (const float*)d_in[6];
    const float* gnn_bias = (const float*)d_in[7];
    const float* bn_gamma = (const float*)d_in[8];
    const float* bn_beta  = (const float*)d_in[9];
    const float* w1       = (const float*)d_in[10];
    const float* w2       = (const float*)d_in[11];
    const float* b2       = (const float*)d_in[12];
    float* out            = (float*)d_out;   // f32 outputs: [out | emb | topk_idx]

    float* ws       = (float*)d_ws;
    float* inv_norm = ws;                       // 512
    int*   topk     = (int*)(ws + 512);         // 10240 ints
    float* s_i      = ws + 512 + N * TOPK;      // 32768
    float* s_j      = s_i + B * N;              // 32768
    float* xl       = s_j + B * N;              // 4194304 (offset 76288, 16B aligned)
    float* gcnemb   = xl + (size_t)B * N * D;   // 4194304
    float* out1     = xl;                       // alias: xl dead after k_attn

    float* out_emb = out + (size_t)B * D * HID;
    float* out_idx = out_emb + (size_t)N * D;

    hipLaunchKernelGGL(k_norm,    dim3(N),             dim3(D),   0, stream, emb, inv_norm);
    hipLaunchKernelGGL(k_topk,    dim3(N),             dim3(256), 0, stream, emb, inv_norm, topk, out_idx);
    hipLaunchKernelGGL(k_emb_out, dim3(64),            dim3(256), 0, stream, emb, out_emb);
    hipLaunchKernelGGL(k_xl,      dim3(N / 32, B),     dim3(256), 0, stream, data, lin_w, xl);
    hipLaunchKernelGGL(k_scores,  dim3(N, B),          dim3(D),   0, stream, xl, emb, att_i, att_j, att_em_i, att_em_j, s_i, s_j);
    hipLaunchKernelGGL(k_attn,    dim3(N, B),          dim3(D),   0, stream, xl, emb, topk, s_i, s_j, gnn_bias, bn_gamma, bn_beta, gcnemb);
    hipLaunchKernelGGL(k_gemm1,   dim3(HID / 64, D / 64, B), dim3(256), 0, stream, gcnemb, w1, out1);
    hipLaunchKernelGGL(k_gemm2,   dim3(HID / 64, D / 64, B), dim3(256), 0, stream, out1, w2, b2, out);
}

// Round 3
// 242.599 us; speedup vs baseline: 1.9551x; 1.9551x over previous
//
#include <hip/hip_runtime.h>
#include <hip/hip_bf16.h>

constexpr int B = 64, N = 512, F_IN = 256, D = 128, TOPK = 20, HID = 512;

typedef __attribute__((ext_vector_type(8))) short short8_t;   // 8 bf16 = one MFMA frag (4 VGPRs)
typedef __attribute__((ext_vector_type(4))) float f32x4;      // MFMA C/D frag

__device__ inline short f2bs(float f) {   // f32 -> bf16 bits (RNE)
    union { __hip_bfloat16 h; short s; } u; u.h = __float2bfloat16(f); return u.s;
}
__device__ inline float bs2f(short s) {   // bf16 bits -> f32 (shift)
    return __uint_as_float(((unsigned)(unsigned short)s) << 16);
}

// ---------------- K0: row norms of emb ----------------
__global__ void k_norm(const float* __restrict__ W, float* __restrict__ inv_norm) {
    int i = blockIdx.x, t = threadIdx.x;  // 128 threads
    float v = W[i * D + t];
    float s = v * v;
    #pragma unroll
    for (int o = 32; o > 0; o >>= 1) s += __shfl_down(s, o);
    __shared__ float red[2];
    if ((t & 63) == 0) red[t >> 6] = s;
    __syncthreads();
    if (t == 0) inv_norm[i] = 1.0f / sqrtf(red[0] + red[1]);
}

// ---------------- K1: cosine row + top-20 (tie: lower index) ----------------
__global__ void k_topk(const float* __restrict__ W, const float* __restrict__ inv_norm,
                       int* __restrict__ topk, float* __restrict__ out_idx) {
    __shared__ float wrow[D];
    __shared__ float cosr[N];
    __shared__ float rval[256];
    __shared__ int   ridx[256];
    int i = blockIdx.x, t = threadIdx.x;  // 256 threads
    if (t < D) wrow[t] = W[i * D + t];
    __syncthreads();
    float inv_i = inv_norm[i];
    for (int j = t; j < N; j += 256) {
        const float* wj = W + j * D;
        float dot = 0.f;
        #pragma unroll
        for (int k = 0; k < D; k += 4) {
            float4 a = *(const float4*)(wj + k);
            dot += wrow[k] * a.x + wrow[k + 1] * a.y + wrow[k + 2] * a.z + wrow[k + 3] * a.w;
        }
        cosr[j] = dot * inv_i * inv_norm[j];
    }
    __syncthreads();
    for (int k = 0; k < TOPK; ++k) {
        float bv = -INFINITY; int bi = 0;
        for (int j = t; j < N; j += 256) {
            float v = cosr[j];
            if (v > bv) { bv = v; bi = j; }
        }
        rval[t] = bv; ridx[t] = bi;
        __syncthreads();
        for (int s = 128; s > 0; s >>= 1) {
            if (t < s) {
                float ov = rval[t + s]; int oi = ridx[t + s];
                if (ov > rval[t] || (ov == rval[t] && oi < ridx[t])) { rval[t] = ov; ridx[t] = oi; }
            }
            __syncthreads();
        }
        if (t == 0) {
            int m = ridx[0];
            topk[i * TOPK + k] = m;
            out_idx[i * TOPK + k] = (float)m;
            cosr[m] = -INFINITY;
        }
        __syncthreads();
    }
}

// ---------------- emb passthrough output (f32) ----------------
__global__ void k_emb_out(const float* __restrict__ emb, float* __restrict__ o) {
    int k = blockIdx.x * 256 + threadIdx.x;
    for (; k < N * D; k += 64 * 256) o[k] = emb[k];
}

// ---------------- transpose: data[b][f][n] f32 -> dataT[b][n][f] bf16 ----------------
// 32x32 LDS tile, +1 pad: both phases 2-way-conflict max (free).
__global__ __launch_bounds__(256) void k_transD(const float* __restrict__ data,
                                                short* __restrict__ dataT) {
    __shared__ float lt[32][33];
    int f0 = blockIdx.x * 32, n0 = blockIdx.y * 32, b = blockIdx.z, t = threadIdx.x;
    {
        int f = t >> 3, ng = (t & 7) * 4;
        float4 v = *(const float4*)&data[((size_t)b * F_IN + f0 + f) * N + n0 + ng];
        lt[f][ng] = v.x; lt[f][ng + 1] = v.y; lt[f][ng + 2] = v.z; lt[f][ng + 3] = v.w;
    }
    __syncthreads();
    {
        int n = t >> 3, fg = (t & 7) * 4;
        short4 w;
        w.x = f2bs(lt[fg + 0][n]); w.y = f2bs(lt[fg + 1][n]);
        w.z = f2bs(lt[fg + 2][n]); w.w = f2bs(lt[fg + 3][n]);
        *(short4*)&dataT[((size_t)b * N + n0 + n) * F_IN + f0 + fg] = w;
    }
}

// ---------------- MFMA GEMM helpers (128x128 block tile, 4 waves of 64x64) --------
// lds row stride 40 shorts (80B): frag ds_read_b128 => 2-way conflicts only (free).
#define MFMA_PROLOG()                                            \
    int t = threadIdx.x;                                         \
    int wid = t >> 6, lane = t & 63;                             \
    int wm = (wid >> 1) * 64, wn = (wid & 1) * 64;               \
    int lr = lane & 15, quad = lane >> 4;                        \
    f32x4 acc[4][4] = {};

#define MFMA_COMPUTE()                                                                 \
    __syncthreads();                                                                   \
    {                                                                                  \
        short8_t af[4], bfr[4];                                                        \
        _Pragma("unroll")                                                              \
        for (int ms = 0; ms < 4; ++ms)                                                 \
            af[ms] = *(const short8_t*)&lds_a[(wm + ms * 16 + lr) * 40 + quad * 8];    \
        _Pragma("unroll")                                                              \
        for (int ns = 0; ns < 4; ++ns)                                                 \
            bfr[ns] = *(const short8_t*)&lds_b[(wn + ns * 16 + lr) * 40 + quad * 8];   \
        _Pragma("unroll")                                                              \
        for (int ms = 0; ms < 4; ++ms)                                                 \
            _Pragma("unroll")                                                          \
            for (int ns = 0; ns < 4; ++ns)                                             \
                acc[ms][ns] = __builtin_amdgcn_mfma_f32_16x16x32_bf16(                 \
                    af[ms], bfr[ns], acc[ms][ns], 0, 0, 0);                            \
    }                                                                                  \
    __syncthreads();

// stage 128x32 bf16 tile from bf16 source (row-major, k-contiguous): pure 16B copies
#define STAGE_BF16(ldst, src, stride, k0)                                              \
    _Pragma("unroll")                                                                  \
    for (int i = 0; i < 2; ++i) {                                                      \
        int lin = t + i * 256, row = lin >> 2, seg = lin & 3;                          \
        *(short8_t*)&ldst[row * 40 + seg * 8] =                                        \
            *(const short8_t*)&(src)[(size_t)row * (stride) + (k0) + seg * 8];         \
    }

// stage 128x32 tile from f32 source (row-major), converting to bf16
#define STAGE_F32(ldst, src, stride, k0)                                               \
    _Pragma("unroll")                                                                  \
    for (int i = 0; i < 2; ++i) {                                                      \
        int lin = t + i * 256, row = lin >> 2, seg = lin & 3;                          \
        const float* p = &(src)[(size_t)row * (stride) + (k0) + seg * 8];              \
        float4 x = *(const float4*)p, y = *(const float4*)(p + 4);                     \
        short8_t v = { f2bs(x.x), f2bs(x.y), f2bs(x.z), f2bs(x.w),                     \
                       f2bs(y.x), f2bs(y.y), f2bs(y.z), f2bs(y.w) };                   \
        *(short8_t*)&ldst[row * 40 + seg * 8] = v;                                     \
    }

// ---------------- xl[b,n,d] (bf16) = dataT[b,n,:] @ lin_w[d,:]  K=256 ----------------
__global__ __launch_bounds__(256) void k_xl(const short* __restrict__ dataT,
                                            const float* __restrict__ lin_w,
                                            short* __restrict__ xlb) {
    __shared__ __align__(16) short lds_a[128 * 40];
    __shared__ __align__(16) short lds_b[128 * 40];
    int n0 = blockIdx.x * 128, b = blockIdx.y;
    MFMA_PROLOG();
    const short* Asrc = dataT + ((size_t)b * N + n0) * F_IN;
    for (int k0 = 0; k0 < F_IN; k0 += 32) {
        STAGE_BF16(lds_a, Asrc, F_IN, k0);
        STAGE_F32(lds_b, lin_w, F_IN, k0);
        MFMA_COMPUTE();
    }
    #pragma unroll
    for (int ms = 0; ms < 4; ++ms)
        #pragma unroll
        for (int ns = 0; ns < 4; ++ns) {
            int mb = wm + ms * 16 + quad * 4, col = wn + ns * 16 + lr;
            #pragma unroll
            for (int r = 0; r < 4; ++r)
                xlb[((size_t)b * N + n0 + mb + r) * D + col] = f2bs(acc[ms][ns][r]);
        }
}

// ---------------- K3: per-node attention scores (bf16 xl) ----------------
__global__ void k_scores(const short* __restrict__ xlb, const float* __restrict__ emb,
                         const float* __restrict__ att_i, const float* __restrict__ att_j,
                         const float* __restrict__ att_em_i, const float* __restrict__ att_em_j,
                         float* __restrict__ s_i, float* __restrict__ s_j) {
    int n = blockIdx.x, b = blockIdx.y, t = threadIdx.x;  // 128 threads
    int v = b * N + n;
    float x = bs2f(xlb[(size_t)v * D + t]), e = emb[n * D + t];
    float si = x * att_i[t] + e * att_em_i[t];
    float sj = x * att_j[t] + e * att_em_j[t];
    #pragma unroll
    for (int o = 32; o > 0; o >>= 1) { si += __shfl_down(si, o); sj += __shfl_down(sj, o); }
    __shared__ float r[4];
    if ((t & 63) == 0) { r[(t >> 6) * 2] = si; r[(t >> 6) * 2 + 1] = sj; }
    __syncthreads();
    if (t == 0) { s_i[v] = r[0] + r[2]; s_j[v] = r[1] + r[3]; }
}

// ---------------- K4: softmax(20) + aggregate + BN/ReLU/gate -> Gt[b][d][n] bf16 -----
__global__ __launch_bounds__(256) void k_attn2(const short* __restrict__ xlb,
                                               const float* __restrict__ emb,
                                               const int* __restrict__ topk,
                                               const float* __restrict__ s_i,
                                               const float* __restrict__ s_j,
                                               const float* __restrict__ gnn_bias,
                                               const float* __restrict__ bn_gamma,
                                               const float* __restrict__ bn_beta,
                                               short* __restrict__ Gt) {
    __shared__ float alph[16][20];
    __shared__ int   js[16][20];
    __shared__ float lt[16][129];
    int n0 = blockIdx.x * 16, b = blockIdx.y, t = threadIdx.x;
    for (int e = t; e < 16 * TOPK; e += 256) {
        int nl = e / TOPK, k = e - nl * TOPK;
        int j = topk[(n0 + nl) * TOPK + k];
        js[nl][k] = j;
        float al = s_i[b * N + n0 + nl] + s_j[b * N + j];
        alph[nl][k] = al >= 0.f ? al : 0.2f * al;
    }
    __syncthreads();
    if (t < 16) {
        float m = -INFINITY;
        for (int k = 0; k < TOPK; ++k) m = fmaxf(m, alph[t][k]);
        float s = 0.f;
        for (int k = 0; k < TOPK; ++k) { float e_ = expf(alph[t][k] - m); alph[t][k] = e_; s += e_; }
        float inv = 1.0f / s;
        for (int k = 0; k < TOPK; ++k) alph[t][k] *= inv;
    }
    __syncthreads();
    {
        int nl = t >> 4, dl = (t & 15) * 8;
        float a[8] = {};
        for (int k = 0; k < TOPK; ++k) {
            float w = alph[nl][k];
            short8_t xv = *(const short8_t*)&xlb[((size_t)b * N + js[nl][k]) * D + dl];
            #pragma unroll
            for (int c = 0; c < 8; ++c) a[c] += w * bs2f(xv[c]);
        }
        const float bnk = 0.9999950000374997f;  // 1/sqrt(1+1e-5)
        #pragma unroll
        for (int c = 0; c < 8; ++c) {
            int d = dl + c;
            float h = (a[c] + gnn_bias[d]) * (bn_gamma[d] * bnk) + bn_beta[d];
            h = fmaxf(h, 0.f);
            lt[nl][d] = h * emb[(n0 + nl) * D + d];
        }
    }
    __syncthreads();
    {
        int d = t >> 1, half = t & 1;
        short8_t v;
        #pragma unroll
        for (int j = 0; j < 8; ++j) v[j] = f2bs(lt[half * 8 + j][d]);
        *(short8_t*)&Gt[((size_t)b * D + d) * N + n0 + half * 8] = v;
    }
}

// ---------------- gemm1: out1[b,d,h] (bf16) = Gt[b,d,:] @ w1[h,:]  K=512 ----------------
__global__ __launch_bounds__(256) void k_gemm1(const short* __restrict__ Gt,
                                               const float* __restrict__ w1,
                                               short* __restrict__ out1) {
    __shared__ __align__(16) short lds_a[128 * 40];
    __shared__ __align__(16) short lds_b[128 * 40];
    int h0 = blockIdx.x * 128, b = blockIdx.y;
    MFMA_PROLOG();
    const short* Asrc = Gt + (size_t)b * D * N;
    const float* Bsrc = w1 + (size_t)h0 * N;
    for (int k0 = 0; k0 < N; k0 += 32) {
        STAGE_BF16(lds_a, Asrc, N, k0);
        STAGE_F32(lds_b, Bsrc, N, k0);
        MFMA_COMPUTE();
    }
    #pragma unroll
    for (int ms = 0; ms < 4; ++ms)
        #pragma unroll
        for (int ns = 0; ns < 4; ++ns) {
            int mb = wm + ms * 16 + quad * 4, col = h0 + wn + ns * 16 + lr;
            #pragma unroll
            for (int r = 0; r < 4; ++r)
                out1[((size_t)b * D + mb + r) * HID + col] = f2bs(acc[ms][ns][r]);
        }
}

// ---------------- gemm2: out[b,d,h2] f32 = sigmoid(out1[b,d,:] @ w2[h2,:] + b2) ---------
__global__ __launch_bounds__(256) void k_gemm2(const short* __restrict__ out1,
                                               const float* __restrict__ w2,
                                               const float* __restrict__ b2,
                                               float* __restrict__ out) {
    __shared__ __align__(16) short lds_a[128 * 40];
    __shared__ __align__(16) short lds_b[128 * 40];
    int h0 = blockIdx.x * 128, b = blockIdx.y;
    MFMA_PROLOG();
    const short* Asrc = out1 + (size_t)b * D * HID;
    const float* Bsrc = w2 + (size_t)h0 * HID;
    for (int k0 = 0; k0 < HID; k0 += 32) {
        STAGE_BF16(lds_a, Asrc, HID, k0);
        STAGE_F32(lds_b, Bsrc, HID, k0);
        MFMA_COMPUTE();
    }
    #pragma unroll
    for (int ms = 0; ms < 4; ++ms)
        #pragma unroll
        for (int ns = 0; ns < 4; ++ns) {
            int mb = wm + ms * 16 + quad * 4, col = h0 + wn + ns * 16 + lr;
            float bias = b2[col];
            #pragma unroll
            for (int r = 0; r < 4; ++r)
                out[((size_t)b * D + mb + r) * HID + col] =
                    1.0f / (1.0f + expf(-(acc[ms][ns][r] + bias)));
        }
}

extern "C" void kernel_launch(void* const* d_in, const int* in_sizes, int n_in,
                              void* d_out, int out_size, void* d_ws, size_t ws_size,
                              hipStream_t stream) {
    const float* data     = (const float*)d_in[0];
    const float* emb      = (const float*)d_in[1];
    const float* lin_w    = (const float*)d_in[2];
    const float* att_i    = (const float*)d_in[3];
    const float* att_j    = (const float*)d_in[4];
    const float* att_em_i = (const float*)d_in[5];
    const float* att_em_j = (const float*)d_in[6];
    const float* gnn_bias = (const float*)d_in[7];
    const float* bn_gamma = (const float*)d_in[8];
    const float* bn_beta  = (const float*)d_in[9];
    const float* w1       = (const float*)d_in[10];
    const float* w2       = (const float*)d_in[11];
    const float* b2       = (const float*)d_in[12];
    float* out            = (float*)d_out;   // f32 outputs: [out | emb | topk_idx]

    float* ws       = (float*)d_ws;
    float* inv_norm = ws;                                  // 512 f32
    int*   topk     = (int*)(ws + 512);                    // 10240 i32
    float* s_i      = ws + 512 + N * TOPK;                 // 32768 f32
    float* s_j      = s_i + B * N;                         // 32768 f32
    // 16 MB region: dataT while alive, then reused as Gt (8MB) + out1 (8MB)
    short* dataT    = (short*)(ws + 76288);                // B*N*F_IN bf16 = 16 MB
    short* Gt       = dataT;                               // B*D*N bf16 = 8 MB (dataT dead)
    short* out1     = dataT + (size_t)B * D * N;           // B*D*HID bf16 = 8 MB
    short* xlb      = dataT + (size_t)B * N * F_IN;        // B*N*D bf16 = 8 MB

    float* out_emb = out + (size_t)B * D * HID;
    float* out_idx = out_emb + (size_t)N * D;

    hipLaunchKernelGGL(k_norm,    dim3(N),              dim3(D),   0, stream, emb, inv_norm);
    hipLaunchKernelGGL(k_topk,    dim3(N),              dim3(256), 0, stream, emb, inv_norm, topk, out_idx);
    hipLaunchKernelGGL(k_emb_out, dim3(64),             dim3(256), 0, stream, emb, out_emb);
    hipLaunchKernelGGL(k_transD,  dim3(F_IN / 32, N / 32, B), dim3(256), 0, stream, data, dataT);
    hipLaunchKernelGGL(k_xl,      dim3(N / 128, B),     dim3(256), 0, stream, dataT, lin_w, xlb);
    hipLaunchKernelGGL(k_scores,  dim3(N, B),           dim3(D),   0, stream, xlb, emb, att_i, att_j, att_em_i, att_em_j, s_i, s_j);
    hipLaunchKernelGGL(k_attn2,   dim3(N / 16, B),      dim3(256), 0, stream, xlb, emb, topk, s_i, s_j, gnn_bias, bn_gamma, bn_beta, Gt);
    hipLaunchKernelGGL(k_gemm1,   dim3(HID / 128, B),   dim3(256), 0, stream, Gt, w1, out1);
    hipLaunchKernelGGL(k_gemm2,   dim3(HID / 128, B),   dim3(256), 0, stream, out1, w2, b2, out);
}

// Round 4
// 228.049 us; speedup vs baseline: 2.0799x; 1.0638x over previous
//
#include <hip/hip_runtime.h>
#include <hip/hip_bf16.h>

constexpr int B = 64, N = 512, F_IN = 256, D = 128, TOPK = 20, HID = 512;

typedef __attribute__((ext_vector_type(8))) short short8_t;   // 8 bf16 = one MFMA frag (4 VGPRs)
typedef __attribute__((ext_vector_type(4))) float f32x4;      // MFMA C/D frag

__device__ inline short f2bs(float f) {   // f32 -> bf16 bits (RNE)
    union { __hip_bfloat16 h; short s; } u; u.h = __float2bfloat16(f); return u.s;
}
__device__ inline float bs2f(short s) {   // bf16 bits -> f32 (shift)
    return __uint_as_float(((unsigned)(unsigned short)s) << 16);
}

// ---------------- K0: row norms of emb + per-node att_em dots ----------------
__global__ void k_norm(const float* __restrict__ W, const float* __restrict__ aei,
                       const float* __restrict__ aej, float* __restrict__ inv_norm,
                       float* __restrict__ ei, float* __restrict__ ej) {
    int n = blockIdx.x, t = threadIdx.x;  // 128 threads
    float w = W[n * D + t];
    float s0 = w * w, s1 = w * aei[t], s2 = w * aej[t];
    #pragma unroll
    for (int o = 32; o > 0; o >>= 1) {
        s0 += __shfl_down(s0, o); s1 += __shfl_down(s1, o); s2 += __shfl_down(s2, o);
    }
    __shared__ float r[6];
    if ((t & 63) == 0) { int q = t >> 6; r[q * 3] = s0; r[q * 3 + 1] = s1; r[q * 3 + 2] = s2; }
    __syncthreads();
    if (t == 0) {
        inv_norm[n] = 1.0f / sqrtf(r[0] + r[3]);
        ei[n] = r[1] + r[4];
        ej[n] = r[2] + r[5];
    }
}

// ---------------- K1: cosine top-20, wave-per-row, register selection ----------------
// block = 128 threads (2 waves), grid = 256: wave owns row i. Lane holds 8 candidates
// j = lane + 64c (ascending c == ascending j for tie-break). No LDS, no barriers.
__global__ __launch_bounds__(128) void k_topk(const float* __restrict__ W,
                                              const float* __restrict__ inv_norm,
                                              int* __restrict__ topk,
                                              float* __restrict__ out_idx) {
    int t = threadIdx.x, wid = t >> 6, lane = t & 63;
    int i = blockIdx.x * 2 + wid;
    float inv_i = inv_norm[i];
    const float* wi = W + (size_t)i * D;
    float v[8];
    #pragma unroll
    for (int c = 0; c < 8; ++c) {
        int j = lane + 64 * c;
        const float* wj = W + (size_t)j * D;
        float dot = 0.f;
        #pragma unroll
        for (int d = 0; d < D; d += 4) {
            float4 a = *(const float4*)(wj + d);
            float4 b = *(const float4*)(wi + d);
            dot += b.x * a.x + b.y * a.y + b.z * a.z + b.w * a.w;
        }
        v[c] = dot * inv_i * inv_norm[j];   // same numerics as passing round
    }
    for (int k = 0; k < TOPK; ++k) {
        float bv = v[0]; int bc = 0;
        #pragma unroll
        for (int c = 1; c < 8; ++c) if (v[c] > bv) { bv = v[c]; bc = c; }  // strict >: lowest j in lane
        int bj = lane + 64 * bc;
        #pragma unroll
        for (int o = 1; o < 64; o <<= 1) {
            float ov = __shfl_xor(bv, o);
            int  oj = __shfl_xor(bj, o);
            if (ov > bv || (ov == bv && oj < bj)) { bv = ov; bj = oj; }
        }
        if (lane == 0) {
            topk[i * TOPK + k] = bj;
            out_idx[i * TOPK + k] = (float)bj;
        }
        int bc6 = bj >> 6;
        bool owner = (bj & 63) == lane;
        #pragma unroll
        for (int c = 0; c < 8; ++c) if (owner && c == bc6) v[c] = -INFINITY;
    }
}

// ---------------- emb passthrough output (f32) ----------------
__global__ void k_emb_out(const float* __restrict__ emb, float* __restrict__ o) {
    int k = blockIdx.x * 256 + threadIdx.x;
    for (; k < N * D; k += 64 * 256) o[k] = emb[k];
}

// ---------------- transpose: data[b][f][n] f32 -> dataT[b][n][f] bf16 ----------------
__global__ __launch_bounds__(256) void k_transD(const float* __restrict__ data,
                                                short* __restrict__ dataT) {
    __shared__ float lt[32][33];
    int f0 = blockIdx.x * 32, n0 = blockIdx.y * 32, b = blockIdx.z, t = threadIdx.x;
    {
        int f = t >> 3, ng = (t & 7) * 4;
        float4 v = *(const float4*)&data[((size_t)b * F_IN + f0 + f) * N + n0 + ng];
        lt[f][ng] = v.x; lt[f][ng + 1] = v.y; lt[f][ng + 2] = v.z; lt[f][ng + 3] = v.w;
    }
    __syncthreads();
    {
        int n = t >> 3, fg = (t & 7) * 4;
        short4 w;
        w.x = f2bs(lt[fg + 0][n]); w.y = f2bs(lt[fg + 1][n]);
        w.z = f2bs(lt[fg + 2][n]); w.w = f2bs(lt[fg + 3][n]);
        *(short4*)&dataT[((size_t)b * N + n0 + n) * F_IN + f0 + fg] = w;
    }
}

// ---------------- MFMA GEMM helpers (128x128 block tile, 4 waves of 64x64) --------
#define MFMA_PROLOG()                                            \
    int t = threadIdx.x;                                         \
    int wid = t >> 6, lane = t & 63;                             \
    int wm = (wid >> 1) * 64, wn = (wid & 1) * 64;               \
    int lr = lane & 15, quad = lane >> 4;                        \
    f32x4 acc[4][4] = {};

#define MFMA_COMPUTE()                                                                 \
    __syncthreads();                                                                   \
    {                                                                                  \
        short8_t af[4], bfr[4];                                                        \
        _Pragma("unroll")                                                              \
        for (int ms = 0; ms < 4; ++ms)                                                 \
            af[ms] = *(const short8_t*)&lds_a[(wm + ms * 16 + lr) * 40 + quad * 8];    \
        _Pragma("unroll")                                                              \
        for (int ns = 0; ns < 4; ++ns)                                                 \
            bfr[ns] = *(const short8_t*)&lds_b[(wn + ns * 16 + lr) * 40 + quad * 8];   \
        _Pragma("unroll")                                                              \
        for (int ms = 0; ms < 4; ++ms)                                                 \
            _Pragma("unroll")                                                          \
            for (int ns = 0; ns < 4; ++ns)                                             \
                acc[ms][ns] = __builtin_amdgcn_mfma_f32_16x16x32_bf16(                 \
                    af[ms], bfr[ns], acc[ms][ns], 0, 0, 0);                            \
    }                                                                                  \
    __syncthreads();

#define STAGE_BF16(ldst, src, stride, k0)                                              \
    _Pragma("unroll")                                                                  \
    for (int i = 0; i < 2; ++i) {                                                      \
        int lin = t + i * 256, row = lin >> 2, seg = lin & 3;                          \
        *(short8_t*)&ldst[row * 40 + seg * 8] =                                        \
            *(const short8_t*)&(src)[(size_t)row * (stride) + (k0) + seg * 8];         \
    }

#define STAGE_F32(ldst, src, stride, k0)                                               \
    _Pragma("unroll")                                                                  \
    for (int i = 0; i < 2; ++i) {                                                      \
        int lin = t + i * 256, row = lin >> 2, seg = lin & 3;                          \
        const float* p = &(src)[(size_t)row * (stride) + (k0) + seg * 8];              \
        float4 x = *(const float4*)p, y = *(const float4*)(p + 4);                     \
        short8_t v = { f2bs(x.x), f2bs(x.y), f2bs(x.z), f2bs(x.w),                     \
                       f2bs(y.x), f2bs(y.y), f2bs(y.z), f2bs(y.w) };                   \
        *(short8_t*)&ldst[row * 40 + seg * 8] = v;                                     \
    }

// ---------------- xl[b,n,d] (bf16) = dataT[b,n,:] @ lin_w[d,:]  K=256 ----------------
__global__ __launch_bounds__(256) void k_xl(const short* __restrict__ dataT,
                                            const float* __restrict__ lin_w,
                                            short* __restrict__ xlb) {
    __shared__ __align__(16) short lds_a[128 * 40];
    __shared__ __align__(16) short lds_b[128 * 40];
    int n0 = blockIdx.x * 128, b = blockIdx.y;
    MFMA_PROLOG();
    const short* Asrc = dataT + ((size_t)b * N + n0) * F_IN;
    for (int k0 = 0; k0 < F_IN; k0 += 32) {
        STAGE_BF16(lds_a, Asrc, F_IN, k0);
        STAGE_F32(lds_b, lin_w, F_IN, k0);
        MFMA_COMPUTE();
    }
    #pragma unroll
    for (int ms = 0; ms < 4; ++ms)
        #pragma unroll
        for (int ns = 0; ns < 4; ++ns) {
            int mb = wm + ms * 16 + quad * 4, col = wn + ns * 16 + lr;
            #pragma unroll
            for (int r = 0; r < 4; ++r)
                xlb[((size_t)b * N + n0 + mb + r) * D + col] = f2bs(acc[ms][ns][r]);
        }
}

// ---------------- K3: attention scores, wave-per-row, no barriers ----------------
// wave w handles v = blockIdx.x*4 + w; lane covers d = lane*2, lane*2+1
__global__ __launch_bounds__(256) void k_scores(const short* __restrict__ xlb,
                                                const float* __restrict__ att_i,
                                                const float* __restrict__ att_j,
                                                const float* __restrict__ ei,
                                                const float* __restrict__ ej,
                                                float* __restrict__ s_i,
                                                float* __restrict__ s_j) {
    int t = threadIdx.x, wid = t >> 6, lane = t & 63;
    int v = blockIdx.x * 4 + wid;
    int n = v & (N - 1);
    unsigned x2 = *(const unsigned*)&xlb[(size_t)v * D + lane * 2];
    float x0 = __uint_as_float((x2 & 0xFFFFu) << 16);
    float x1 = __uint_as_float(x2 & 0xFFFF0000u);
    float2 ai = *(const float2*)&att_i[lane * 2];
    float2 aj = *(const float2*)&att_j[lane * 2];
    float si = x0 * ai.x + x1 * ai.y;
    float sj = x0 * aj.x + x1 * aj.y;
    #pragma unroll
    for (int o = 32; o > 0; o >>= 1) { si += __shfl_down(si, o); sj += __shfl_down(sj, o); }
    if (lane == 0) { s_i[v] = si + ei[n]; s_j[v] = sj + ej[n]; }
}

// ---------------- K4: softmax(20) + aggregate + BN/ReLU/gate -> Gt[b][d][n] bf16 -----
__global__ __launch_bounds__(256) void k_attn2(const short* __restrict__ xlb,
                                               const float* __restrict__ emb,
                                               const int* __restrict__ topk,
                                               const float* __restrict__ s_i,
                                               const float* __restrict__ s_j,
                                               const float* __restrict__ gnn_bias,
                                               const float* __restrict__ bn_gamma,
                                               const float* __restrict__ bn_beta,
                                               short* __restrict__ Gt) {
    __shared__ float alph[16][20];
    __shared__ int   js[16][20];
    __shared__ float lt[16][129];
    int n0 = blockIdx.x * 16, b = blockIdx.y, t = threadIdx.x;
    for (int e = t; e < 16 * TOPK; e += 256) {
        int nl = e / TOPK, k = e - nl * TOPK;
        int j = topk[(n0 + nl) * TOPK + k];
        js[nl][k] = j;
        float al = s_i[b * N + n0 + nl] + s_j[b * N + j];
        alph[nl][k] = al >= 0.f ? al : 0.2f * al;
    }
    __syncthreads();
    if (t < 16) {
        float m = -INFINITY;
        for (int k = 0; k < TOPK; ++k) m = fmaxf(m, alph[t][k]);
        float s = 0.f;
        for (int k = 0; k < TOPK; ++k) { float e_ = expf(alph[t][k] - m); alph[t][k] = e_; s += e_; }
        float inv = 1.0f / s;
        for (int k = 0; k < TOPK; ++k) alph[t][k] *= inv;
    }
    __syncthreads();
    {
        int nl = t >> 4, dl = (t & 15) * 8;
        float a[8] = {};
        for (int k = 0; k < TOPK; ++k) {
            float w = alph[nl][k];
            short8_t xv = *(const short8_t*)&xlb[((size_t)b * N + js[nl][k]) * D + dl];
            #pragma unroll
            for (int c = 0; c < 8; ++c) a[c] += w * bs2f(xv[c]);
        }
        const float bnk = 0.9999950000374997f;  // 1/sqrt(1+1e-5)
        #pragma unroll
        for (int c = 0; c < 8; ++c) {
            int d = dl + c;
            float h = (a[c] + gnn_bias[d]) * (bn_gamma[d] * bnk) + bn_beta[d];
            h = fmaxf(h, 0.f);
            lt[nl][d] = h * emb[(n0 + nl) * D + d];
        }
    }
    __syncthreads();
    {
        int d = t >> 1, half = t & 1;
        short8_t v;
        #pragma unroll
        for (int j = 0; j < 8; ++j) v[j] = f2bs(lt[half * 8 + j][d]);
        *(short8_t*)&Gt[((size_t)b * D + d) * N + n0 + half * 8] = v;
    }
}

// ---------------- gemm1: out1[b,d,h] (bf16) = Gt[b,d,:] @ w1[h,:]  K=512 ----------------
__global__ __launch_bounds__(256) void k_gemm1(const short* __restrict__ Gt,
                                               const float* __restrict__ w1,
                                               short* __restrict__ out1) {
    __shared__ __align__(16) short lds_a[128 * 40];
    __shared__ __align__(16) short lds_b[128 * 40];
    int h0 = blockIdx.x * 128, b = blockIdx.y;
    MFMA_PROLOG();
    const short* Asrc = Gt + (size_t)b * D * N;
    const float* Bsrc = w1 + (size_t)h0 * N;
    for (int k0 = 0; k0 < N; k0 += 32) {
        STAGE_BF16(lds_a, Asrc, N, k0);
        STAGE_F32(lds_b, Bsrc, N, k0);
        MFMA_COMPUTE();
    }
    #pragma unroll
    for (int ms = 0; ms < 4; ++ms)
        #pragma unroll
        for (int ns = 0; ns < 4; ++ns) {
            int mb = wm + ms * 16 + quad * 4, col = h0 + wn + ns * 16 + lr;
            #pragma unroll
            for (int r = 0; r < 4; ++r)
                out1[((size_t)b * D + mb + r) * HID + col] = f2bs(acc[ms][ns][r]);
        }
}

// ---------------- gemm2: out[b,d,h2] f32 = sigmoid(out1[b,d,:] @ w2[h2,:] + b2) ---------
__global__ __launch_bounds__(256) void k_gemm2(const short* __restrict__ out1,
                                               const float* __restrict__ w2,
                                               const float* __restrict__ b2,
                                               float* __restrict__ out) {
    __shared__ __align__(16) short lds_a[128 * 40];
    __shared__ __align__(16) short lds_b[128 * 40];
    int h0 = blockIdx.x * 128, b = blockIdx.y;
    MFMA_PROLOG();
    const short* Asrc = out1 + (size_t)b * D * HID;
    const float* Bsrc = w2 + (size_t)h0 * HID;
    for (int k0 = 0; k0 < HID; k0 += 32) {
        STAGE_BF16(lds_a, Asrc, HID, k0);
        STAGE_F32(lds_b, Bsrc, HID, k0);
        MFMA_COMPUTE();
    }
    #pragma unroll
    for (int ms = 0; ms < 4; ++ms)
        #pragma unroll
        for (int ns = 0; ns < 4; ++ns) {
            int mb = wm + ms * 16 + quad * 4, col = h0 + wn + ns * 16 + lr;
            float bias = b2[col];
            #pragma unroll
            for (int r = 0; r < 4; ++r)
                out[((size_t)b * D + mb + r) * HID + col] =
                    1.0f / (1.0f + expf(-(acc[ms][ns][r] + bias)));
        }
}

extern "C" void kernel_launch(void* const* d_in, const int* in_sizes, int n_in,
                              void* d_out, int out_size, void* d_ws, size_t ws_size,
                              hipStream_t stream) {
    const float* data     = (const float*)d_in[0];
    const float* emb      = (const float*)d_in[1];
    const float* lin_w    = (const float*)d_in[2];
    const float* att_i    = (const float*)d_in[3];
    const float* att_j    = (const float*)d_in[4];
    const float* att_em_i = (const float*)d_in[5];
    const float* att_em_j = (const float*)d_in[6];
    const float* gnn_bias = (const float*)d_in[7];
    const float* bn_gamma = (const float*)d_in[8];
    const float* bn_beta  = (const float*)d_in[9];
    const float* w1       = (const float*)d_in[10];
    const float* w2       = (const float*)d_in[11];
    const float* b2       = (const float*)d_in[12];
    float* out            = (float*)d_out;   // f32 outputs: [out | emb | topk_idx]

    float* ws       = (float*)d_ws;
    float* inv_norm = ws;                                  // 512 f32
    float* ei       = ws + 512;                            // 512 f32
    float* ej       = ws + 1024;                           // 512 f32
    int*   topk     = (int*)(ws + 1536);                   // 10240 i32
    float* s_i      = ws + 1536 + N * TOPK;                // 32768 f32  (off 11776)
    float* s_j      = s_i + B * N;                         // 32768 f32  (off 44544)
    short* dataT    = (short*)(ws + 77312);                // B*N*F_IN bf16 = 16 MB (16B aligned)
    short* Gt       = dataT;                               // B*D*N bf16 = 8 MB (dataT dead)
    short* out1     = dataT + (size_t)B * D * N;           // B*D*HID bf16 = 8 MB
    short* xlb      = dataT + (size_t)B * N * F_IN;        // B*N*D bf16 = 8 MB

    float* out_emb = out + (size_t)B * D * HID;
    float* out_idx = out_emb + (size_t)N * D;

    hipLaunchKernelGGL(k_norm,    dim3(N),              dim3(D),   0, stream, emb, att_em_i, att_em_j, inv_norm, ei, ej);
    hipLaunchKernelGGL(k_topk,    dim3(N / 2),          dim3(128), 0, stream, emb, inv_norm, topk, out_idx);
    hipLaunchKernelGGL(k_emb_out, dim3(64),             dim3(256), 0, stream, emb, out_emb);
    hipLaunchKernelGGL(k_transD,  dim3(F_IN / 32, N / 32, B), dim3(256), 0, stream, data, dataT);
    hipLaunchKernelGGL(k_xl,      dim3(N / 128, B),     dim3(256), 0, stream, dataT, lin_w, xlb);
    hipLaunchKernelGGL(k_scores,  dim3(B * N / 4),      dim3(256), 0, stream, xlb, att_i, att_j, ei, ej, s_i, s_j);
    hipLaunchKernelGGL(k_attn2,   dim3(N / 16, B),      dim3(256), 0, stream, xlb, emb, topk, s_i, s_j, gnn_bias, bn_gamma, bn_beta, Gt);
    hipLaunchKernelGGL(k_gemm1,   dim3(HID / 128, B),   dim3(256), 0, stream, Gt, w1, out1);
    hipLaunchKernelGGL(k_gemm2,   dim3(HID / 128, B),   dim3(256), 0, stream, out1, w2, b2, out);
}

// Round 5
// 216.052 us; speedup vs baseline: 2.1954x; 1.0555x over previous
//
#include <hip/hip_runtime.h>
#include <hip/hip_bf16.h>

constexpr int B = 64, N = 512, F_IN = 256, D = 128, TOPK = 20, HID = 512;

typedef __attribute__((ext_vector_type(8))) short short8_t;   // 8 bf16 = one MFMA frag (4 VGPRs)
typedef __attribute__((ext_vector_type(4))) float f32x4;      // MFMA C/D frag

__device__ inline short f2bs(float f) {   // f32 -> bf16 bits (RNE)
    union { __hip_bfloat16 h; short s; } u; u.h = __float2bfloat16(f); return u.s;
}
__device__ inline float bs2f(short s) {   // bf16 bits -> f32 (shift)
    return __uint_as_float(((unsigned)(unsigned short)s) << 16);
}

// ---------------- K0: row norms of emb + per-node att_em dots ----------------
__global__ void k_norm(const float* __restrict__ W, const float* __restrict__ aei,
                       const float* __restrict__ aej, float* __restrict__ inv_norm,
                       float* __restrict__ ei, float* __restrict__ ej) {
    int n = blockIdx.x, t = threadIdx.x;  // 128 threads
    float w = W[n * D + t];
    float s0 = w * w, s1 = w * aei[t], s2 = w * aej[t];
    #pragma unroll
    for (int o = 32; o > 0; o >>= 1) {
        s0 += __shfl_down(s0, o); s1 += __shfl_down(s1, o); s2 += __shfl_down(s2, o);
    }
    __shared__ float r[6];
    if ((t & 63) == 0) { int q = t >> 6; r[q * 3] = s0; r[q * 3 + 1] = s1; r[q * 3 + 2] = s2; }
    __syncthreads();
    if (t == 0) {
        inv_norm[n] = 1.0f / sqrtf(r[0] + r[3]);
        ei[n] = r[1] + r[4];
        ej[n] = r[2] + r[5];
    }
}

// ---------------- K1a: cos[i][j] = (W[i].W[j]) * inv_i * inv_j  (fp32 tiled GEMM) -----
// 64x64 tile, 256 threads, 4x4 micro-tile, K=128 in chunks of 32.
__global__ __launch_bounds__(256) void k_cos(const float* __restrict__ W,
                                             const float* __restrict__ inv_norm,
                                             float* __restrict__ cosm) {
    __shared__ float la[32][64];  // [kk][il]
    __shared__ float lb[32][64];  // [kk][jl]
    int j0 = blockIdx.x * 64, i0 = blockIdx.y * 64, t = threadIdx.x;
    int ix = (t & 15) * 4, jx = (t >> 4) * 4;
    float acc[4][4] = {};
    for (int k0 = 0; k0 < D; k0 += 32) {
        #pragma unroll
        for (int i = 0; i < 8; ++i) {
            int lin = t + i * 256, rl = lin & 63, kk = lin >> 6;
            la[kk][rl] = W[(size_t)(i0 + rl) * D + k0 + kk];
            lb[kk][rl] = W[(size_t)(j0 + rl) * D + k0 + kk];
        }
        __syncthreads();
        #pragma unroll
        for (int kk = 0; kk < 32; ++kk) {
            float4 a = *(const float4*)&la[kk][ix];
            float4 b = *(const float4*)&lb[kk][jx];
            float av[4] = {a.x, a.y, a.z, a.w}, bv[4] = {b.x, b.y, b.z, b.w};
            #pragma unroll
            for (int ii = 0; ii < 4; ++ii)
                #pragma unroll
                for (int jj = 0; jj < 4; ++jj) acc[ii][jj] += av[ii] * bv[jj];
        }
        __syncthreads();
    }
    #pragma unroll
    for (int ii = 0; ii < 4; ++ii) {
        float inv_i = inv_norm[i0 + ix + ii];
        float4 v;
        v.x = acc[ii][0] * inv_i * inv_norm[j0 + jx + 0];
        v.y = acc[ii][1] * inv_i * inv_norm[j0 + jx + 1];
        v.z = acc[ii][2] * inv_i * inv_norm[j0 + jx + 2];
        v.w = acc[ii][3] * inv_i * inv_norm[j0 + jx + 3];
        *(float4*)&cosm[(size_t)(i0 + ix + ii) * N + j0 + jx] = v;
    }
}

// ---------------- K1b: top-20 selection from cos row, wave-per-row ----------------
// lane holds v[c] = cos[i][lane*8+c]; 20x (register scan + 6-step butterfly).
__global__ __launch_bounds__(256) void k_sel(const float* __restrict__ cosm,
                                             int* __restrict__ topk,
                                             float* __restrict__ out_idx) {
    int t = threadIdx.x, wid = t >> 6, lane = t & 63;
    int i = blockIdx.x * 4 + wid;
    float4 p0 = *(const float4*)&cosm[(size_t)i * N + lane * 8];
    float4 p1 = *(const float4*)&cosm[(size_t)i * N + lane * 8 + 4];
    float v[8] = {p0.x, p0.y, p0.z, p0.w, p1.x, p1.y, p1.z, p1.w};
    for (int k = 0; k < TOPK; ++k) {
        float bv = v[0]; int bc = 0;
        #pragma unroll
        for (int c = 1; c < 8; ++c) if (v[c] > bv) { bv = v[c]; bc = c; }  // strict >: lowest j wins
        int bj = lane * 8 + bc;
        #pragma unroll
        for (int o = 1; o < 64; o <<= 1) {
            float ov = __shfl_xor(bv, o);
            int  oj = __shfl_xor(bj, o);
            if (ov > bv || (ov == bv && oj < bj)) { bv = ov; bj = oj; }
        }
        if (lane == 0) {
            topk[i * TOPK + k] = bj;
            out_idx[i * TOPK + k] = (float)bj;
        }
        int oc = bj & 7; bool owner = (bj >> 3) == lane;
        #pragma unroll
        for (int c = 0; c < 8; ++c) if (owner && c == oc) v[c] = -INFINITY;
    }
}

// ---------------- emb passthrough output (f32) ----------------
__global__ void k_emb_out(const float* __restrict__ emb, float* __restrict__ o) {
    int k = blockIdx.x * 256 + threadIdx.x;
    for (; k < N * D; k += 64 * 256) o[k] = emb[k];
}

// ---------------- transpose: data[b][f][n] f32 -> dataT[b][n][f] bf16 ----------------
__global__ __launch_bounds__(256) void k_transD(const float* __restrict__ data,
                                                short* __restrict__ dataT) {
    __shared__ float lt[32][33];
    int f0 = blockIdx.x * 32, n0 = blockIdx.y * 32, b = blockIdx.z, t = threadIdx.x;
    {
        int f = t >> 3, ng = (t & 7) * 4;
        float4 v = *(const float4*)&data[((size_t)b * F_IN + f0 + f) * N + n0 + ng];
        lt[f][ng] = v.x; lt[f][ng + 1] = v.y; lt[f][ng + 2] = v.z; lt[f][ng + 3] = v.w;
    }
    __syncthreads();
    {
        int n = t >> 3, fg = (t & 7) * 4;
        short4 w;
        w.x = f2bs(lt[fg + 0][n]); w.y = f2bs(lt[fg + 1][n]);
        w.z = f2bs(lt[fg + 2][n]); w.w = f2bs(lt[fg + 3][n]);
        *(short4*)&dataT[((size_t)b * N + n0 + n) * F_IN + f0 + fg] = w;
    }
}

// ---------------- MFMA GEMM helpers (128x128 block tile, 4 waves of 64x64) --------
#define MFMA_PROLOG()                                            \
    int t = threadIdx.x;                                         \
    int wid = t >> 6, lane = t & 63;                             \
    int wm = (wid >> 1) * 64, wn = (wid & 1) * 64;               \
    int lr = lane & 15, quad = lane >> 4;                        \
    f32x4 acc[4][4] = {};

#define MFMA_COMPUTE()                                                                 \
    __syncthreads();                                                                   \
    {                                                                                  \
        short8_t af[4], bfr[4];                                                        \
        _Pragma("unroll")                                                              \
        for (int ms = 0; ms < 4; ++ms)                                                 \
            af[ms] = *(const short8_t*)&lds_a[(wm + ms * 16 + lr) * 40 + quad * 8];    \
        _Pragma("unroll")                                                              \
        for (int ns = 0; ns < 4; ++ns)                                                 \
            bfr[ns] = *(const short8_t*)&lds_b[(wn + ns * 16 + lr) * 40 + quad * 8];   \
        _Pragma("unroll")                                                              \
        for (int ms = 0; ms < 4; ++ms)                                                 \
            _Pragma("unroll")                                                          \
            for (int ns = 0; ns < 4; ++ns)                                             \
                acc[ms][ns] = __builtin_amdgcn_mfma_f32_16x16x32_bf16(                 \
                    af[ms], bfr[ns], acc[ms][ns], 0, 0, 0);                            \
    }                                                                                  \
    __syncthreads();

#define STAGE_BF16(ldst, src, stride, k0)                                              \
    _Pragma("unroll")                                                                  \
    for (int i = 0; i < 2; ++i) {                                                      \
        int lin = t + i * 256, row = lin >> 2, seg = lin & 3;                          \
        *(short8_t*)&ldst[row * 40 + seg * 8] =                                        \
            *(const short8_t*)&(src)[(size_t)row * (stride) + (k0) + seg * 8];         \
    }

#define STAGE_F32(ldst, src, stride, k0)                                               \
    _Pragma("unroll")                                                                  \
    for (int i = 0; i < 2; ++i) {                                                      \
        int lin = t + i * 256, row = lin >> 2, seg = lin & 3;                          \
        const float* p = &(src)[(size_t)row * (stride) + (k0) + seg * 8];              \
        float4 x = *(const float4*)p, y = *(const float4*)(p + 4);                     \
        short8_t v = { f2bs(x.x), f2bs(x.y), f2bs(x.z), f2bs(x.w),                     \
                       f2bs(y.x), f2bs(y.y), f2bs(y.z), f2bs(y.w) };                   \
        *(short8_t*)&ldst[row * 40 + seg * 8] = v;                                     \
    }

// ---------------- xl[b,n,d] (bf16) = dataT[b,n,:] @ lin_w[d,:]  K=256 ----------------
__global__ __launch_bounds__(256) void k_xl(const short* __restrict__ dataT,
                                            const float* __restrict__ lin_w,
                                            short* __restrict__ xlb) {
    __shared__ __align__(16) short lds_a[128 * 40];
    __shared__ __align__(16) short lds_b[128 * 40];
    int n0 = blockIdx.x * 128, b = blockIdx.y;
    MFMA_PROLOG();
    const short* Asrc = dataT + ((size_t)b * N + n0) * F_IN;
    for (int k0 = 0; k0 < F_IN; k0 += 32) {
        STAGE_BF16(lds_a, Asrc, F_IN, k0);
        STAGE_F32(lds_b, lin_w, F_IN, k0);
        MFMA_COMPUTE();
    }
    #pragma unroll
    for (int ms = 0; ms < 4; ++ms)
        #pragma unroll
        for (int ns = 0; ns < 4; ++ns) {
            int mb = wm + ms * 16 + quad * 4, col = wn + ns * 16 + lr;
            #pragma unroll
            for (int r = 0; r < 4; ++r)
                xlb[((size_t)b * N + n0 + mb + r) * D + col] = f2bs(acc[ms][ns][r]);
        }
}

// ---------------- K3: attention scores, wave-per-row, no barriers ----------------
__global__ __launch_bounds__(256) void k_scores(const short* __restrict__ xlb,
                                                const float* __restrict__ att_i,
                                                const float* __restrict__ att_j,
                                                const float* __restrict__ ei,
                                                const float* __restrict__ ej,
                                                float* __restrict__ s_i,
                                                float* __restrict__ s_j) {
    int t = threadIdx.x, wid = t >> 6, lane = t & 63;
    int v = blockIdx.x * 4 + wid;
    int n = v & (N - 1);
    unsigned x2 = *(const unsigned*)&xlb[(size_t)v * D + lane * 2];
    float x0 = __uint_as_float((x2 & 0xFFFFu) << 16);
    float x1 = __uint_as_float(x2 & 0xFFFF0000u);
    float2 ai = *(const float2*)&att_i[lane * 2];
    float2 aj = *(const float2*)&att_j[lane * 2];
    float si = x0 * ai.x + x1 * ai.y;
    float sj = x0 * aj.x + x1 * aj.y;
    #pragma unroll
    for (int o = 32; o > 0; o >>= 1) { si += __shfl_down(si, o); sj += __shfl_down(sj, o); }
    if (lane == 0) { s_i[v] = si + ei[n]; s_j[v] = sj + ej[n]; }
}

// ---------------- K4: softmax(20) + aggregate + BN/ReLU/gate -> Gt[b][d][n] bf16 -----
__global__ __launch_bounds__(256) void k_attn2(const short* __restrict__ xlb,
                                               const float* __restrict__ emb,
                                               const int* __restrict__ topk,
                                               const float* __restrict__ s_i,
                                               const float* __restrict__ s_j,
                                               const float* __restrict__ gnn_bias,
                                               const float* __restrict__ bn_gamma,
                                               const float* __restrict__ bn_beta,
                                               short* __restrict__ Gt) {
    __shared__ float alph[16][20];
    __shared__ int   js[16][20];
    __shared__ float lt[16][129];
    int n0 = blockIdx.x * 16, b = blockIdx.y, t = threadIdx.x;
    for (int e = t; e < 16 * TOPK; e += 256) {
        int nl = e / TOPK, k = e - nl * TOPK;
        int j = topk[(n0 + nl) * TOPK + k];
        js[nl][k] = j;
        float al = s_i[b * N + n0 + nl] + s_j[b * N + j];
        alph[nl][k] = al >= 0.f ? al : 0.2f * al;
    }
    __syncthreads();
    if (t < 16) {
        float m = -INFINITY;
        for (int k = 0; k < TOPK; ++k) m = fmaxf(m, alph[t][k]);
        float s = 0.f;
        for (int k = 0; k < TOPK; ++k) { float e_ = expf(alph[t][k] - m); alph[t][k] = e_; s += e_; }
        float inv = 1.0f / s;
        for (int k = 0; k < TOPK; ++k) alph[t][k] *= inv;
    }
    __syncthreads();
    {
        int nl = t >> 4, dl = (t & 15) * 8;
        float a[8] = {};
        for (int k = 0; k < TOPK; ++k) {
            float w = alph[nl][k];
            short8_t xv = *(const short8_t*)&xlb[((size_t)b * N + js[nl][k]) * D + dl];
            #pragma unroll
            for (int c = 0; c < 8; ++c) a[c] += w * bs2f(xv[c]);
        }
        const float bnk = 0.9999950000374997f;  // 1/sqrt(1+1e-5)
        #pragma unroll
        for (int c = 0; c < 8; ++c) {
            int d = dl + c;
            float h = (a[c] + gnn_bias[d]) * (bn_gamma[d] * bnk) + bn_beta[d];
            h = fmaxf(h, 0.f);
            lt[nl][d] = h * emb[(n0 + nl) * D + d];
        }
    }
    __syncthreads();
    {
        int d = t >> 1, half = t & 1;
        short8_t v;
        #pragma unroll
        for (int j = 0; j < 8; ++j) v[j] = f2bs(lt[half * 8 + j][d]);
        *(short8_t*)&Gt[((size_t)b * D + d) * N + n0 + half * 8] = v;
    }
}

// ---------------- gemm1: out1[b,d,h] (bf16) = Gt[b,d,:] @ w1[h,:]  K=512 ----------------
__global__ __launch_bounds__(256) void k_gemm1(const short* __restrict__ Gt,
                                               const float* __restrict__ w1,
                                               short* __restrict__ out1) {
    __shared__ __align__(16) short lds_a[128 * 40];
    __shared__ __align__(16) short lds_b[128 * 40];
    int h0 = blockIdx.x * 128, b = blockIdx.y;
    MFMA_PROLOG();
    const short* Asrc = Gt + (size_t)b * D * N;
    const float* Bsrc = w1 + (size_t)h0 * N;
    for (int k0 = 0; k0 < N; k0 += 32) {
        STAGE_BF16(lds_a, Asrc, N, k0);
        STAGE_F32(lds_b, Bsrc, N, k0);
        MFMA_COMPUTE();
    }
    #pragma unroll
    for (int ms = 0; ms < 4; ++ms)
        #pragma unroll
        for (int ns = 0; ns < 4; ++ns) {
            int mb = wm + ms * 16 + quad * 4, col = h0 + wn + ns * 16 + lr;
            #pragma unroll
            for (int r = 0; r < 4; ++r)
                out1[((size_t)b * D + mb + r) * HID + col] = f2bs(acc[ms][ns][r]);
        }
}

// ---------------- gemm2: out[b,d,h2] f32 = sigmoid(out1[b,d,:] @ w2[h2,:] + b2) ---------
__global__ __launch_bounds__(256) void k_gemm2(const short* __restrict__ out1,
                                               const float* __restrict__ w2,
                                               const float* __restrict__ b2,
                                               float* __restrict__ out) {
    __shared__ __align__(16) short lds_a[128 * 40];
    __shared__ __align__(16) short lds_b[128 * 40];
    int h0 = blockIdx.x * 128, b = blockIdx.y;
    MFMA_PROLOG();
    const short* Asrc = out1 + (size_t)b * D * HID;
    const float* Bsrc = w2 + (size_t)h0 * HID;
    for (int k0 = 0; k0 < HID; k0 += 32) {
        STAGE_BF16(lds_a, Asrc, HID, k0);
        STAGE_F32(lds_b, Bsrc, HID, k0);
        MFMA_COMPUTE();
    }
    #pragma unroll
    for (int ms = 0; ms < 4; ++ms)
        #pragma unroll
        for (int ns = 0; ns < 4; ++ns) {
            int mb = wm + ms * 16 + quad * 4, col = h0 + wn + ns * 16 + lr;
            float bias = b2[col];
            #pragma unroll
            for (int r = 0; r < 4; ++r)
                out[((size_t)b * D + mb + r) * HID + col] =
                    1.0f / (1.0f + expf(-(acc[ms][ns][r] + bias)));
        }
}

extern "C" void kernel_launch(void* const* d_in, const int* in_sizes, int n_in,
                              void* d_out, int out_size, void* d_ws, size_t ws_size,
                              hipStream_t stream) {
    const float* data     = (const float*)d_in[0];
    const float* emb      = (const float*)d_in[1];
    const float* lin_w    = (const float*)d_in[2];
    const float* att_i    = (const float*)d_in[3];
    const float* att_j    = (const float*)d_in[4];
    const float* att_em_i = (const float*)d_in[5];
    const float* att_em_j = (const float*)d_in[6];
    const float* gnn_bias = (const float*)d_in[7];
    const float* bn_gamma = (const float*)d_in[8];
    const float* bn_beta  = (const float*)d_in[9];
    const float* w1       = (const float*)d_in[10];
    const float* w2       = (const float*)d_in[11];
    const float* b2       = (const float*)d_in[12];
    float* out            = (float*)d_out;   // f32 outputs: [out | emb | topk_idx]

    float* ws       = (float*)d_ws;
    float* inv_norm = ws;                                  // 512 f32
    float* ei       = ws + 512;                            // 512 f32
    float* ej       = ws + 1024;                           // 512 f32
    int*   topk     = (int*)(ws + 1536);                   // 10240 i32
    float* s_i      = ws + 1536 + N * TOPK;                // 32768 f32  (off 11776)
    float* s_j      = s_i + B * N;                         // 32768 f32  (off 44544)
    short* dataT    = (short*)(ws + 77312);                // B*N*F_IN bf16 = 16 MB (16B aligned)
    float* cosm     = (float*)dataT;                       // 1 MB, dead before transD writes dataT
    short* Gt       = dataT;                               // B*D*N bf16 = 8 MB (dataT dead)
    short* out1     = dataT + (size_t)B * D * N;           // B*D*HID bf16 = 8 MB
    short* xlb      = dataT + (size_t)B * N * F_IN;        // B*N*D bf16 = 8 MB

    float* out_emb = out + (size_t)B * D * HID;
    float* out_idx = out_emb + (size_t)N * D;

    hipLaunchKernelGGL(k_norm,    dim3(N),              dim3(D),   0, stream, emb, att_em_i, att_em_j, inv_norm, ei, ej);
    hipLaunchKernelGGL(k_cos,     dim3(N / 64, N / 64), dim3(256), 0, stream, emb, inv_norm, cosm);
    hipLaunchKernelGGL(k_sel,     dim3(N / 4),          dim3(256), 0, stream, cosm, topk, out_idx);
    hipLaunchKernelGGL(k_emb_out, dim3(64),             dim3(256), 0, stream, emb, out_emb);
    hipLaunchKernelGGL(k_transD,  dim3(F_IN / 32, N / 32, B), dim3(256), 0, stream, data, dataT);
    hipLaunchKernelGGL(k_xl,      dim3(N / 128, B),     dim3(256), 0, stream, dataT, lin_w, xlb);
    hipLaunchKernelGGL(k_scores,  dim3(B * N / 4),      dim3(256), 0, stream, xlb, att_i, att_j, ei, ej, s_i, s_j);
    hipLaunchKernelGGL(k_attn2,   dim3(N / 16, B),      dim3(256), 0, stream, xlb, emb, topk, s_i, s_j, gnn_bias, bn_gamma, bn_beta, Gt);
    hipLaunchKernelGGL(k_gemm1,   dim3(HID / 128, B),   dim3(256), 0, stream, Gt, w1, out1);
    hipLaunchKernelGGL(k_gemm2,   dim3(HID / 128, B),   dim3(256), 0, stream, out1, w2, b2, out);
}

// Round 6
// 200.951 us; speedup vs baseline: 2.3603x; 1.0751x over previous
//
#include <hip/hip_runtime.h>
#include <hip/hip_bf16.h>

constexpr int B = 64, N = 512, F_IN = 256, D = 128, TOPK = 20, HID = 512;

typedef __attribute__((ext_vector_type(8))) short short8_t;   // 8 bf16 = one MFMA frag (4 VGPRs)
typedef __attribute__((ext_vector_type(4))) float f32x4;      // MFMA C/D frag

__device__ inline short f2bs(float f) {   // f32 -> bf16 bits (RNE)
    union { __hip_bfloat16 h; short s; } u; u.h = __float2bfloat16(f); return u.s;
}
__device__ inline float bs2f(short s) {   // bf16 bits -> f32 (shift)
    return __uint_as_float(((unsigned)(unsigned short)s) << 16);
}

// stage ROWS x 32 bf16 tile into LDS (stride 40 shorts); ITERS = ROWS/64
template<int ITERS>
__device__ inline void stage_bf16(short* ldst, const short* __restrict__ src,
                                  int stride, int k0, int t) {
    #pragma unroll
    for (int i = 0; i < ITERS; ++i) {
        int lin = t + i * 256, row = lin >> 2, seg = lin & 3;
        *(short8_t*)&ldst[row * 40 + seg * 8] =
            *(const short8_t*)&src[(size_t)row * stride + k0 + seg * 8];
    }
}
template<int ITERS>
__device__ inline void stage_f32(short* ldst, const float* __restrict__ src,
                                 int stride, int k0, int t) {
    #pragma unroll
    for (int i = 0; i < ITERS; ++i) {
        int lin = t + i * 256, row = lin >> 2, seg = lin & 3;
        const float* p = &src[(size_t)row * stride + k0 + seg * 8];
        float4 x = *(const float4*)p, y = *(const float4*)(p + 4);
        short8_t v = { f2bs(x.x), f2bs(x.y), f2bs(x.z), f2bs(x.w),
                       f2bs(y.x), f2bs(y.y), f2bs(y.z), f2bs(y.w) };
        *(short8_t*)&ldst[row * 40 + seg * 8] = v;
    }
}

// MS x NS grid of 16x16x32 MFMAs from staged LDS tiles
template<int MS, int NS>
__device__ inline void mfma_tiles(const short* lds_a, const short* lds_b,
                                  f32x4 (&acc)[MS][NS], int wm, int wn, int lr, int quad) {
    short8_t af[MS], bf[NS];
    #pragma unroll
    for (int ms = 0; ms < MS; ++ms)
        af[ms] = *(const short8_t*)&lds_a[(wm + ms * 16 + lr) * 40 + quad * 8];
    #pragma unroll
    for (int ns = 0; ns < NS; ++ns)
        bf[ns] = *(const short8_t*)&lds_b[(wn + ns * 16 + lr) * 40 + quad * 8];
    #pragma unroll
    for (int ms = 0; ms < MS; ++ms)
        #pragma unroll
        for (int ns = 0; ns < NS; ++ns)
            acc[ms][ns] = __builtin_amdgcn_mfma_f32_16x16x32_bf16(af[ms], bf[ns], acc[ms][ns], 0, 0, 0);
}

// ---------------- K0: row norms + att_em dots + emb passthrough copy ----------------
__global__ void k_norm(const float* __restrict__ W, const float* __restrict__ aei,
                       const float* __restrict__ aej, float* __restrict__ inv_norm,
                       float* __restrict__ ei, float* __restrict__ ej,
                       float* __restrict__ out_emb) {
    int n = blockIdx.x, t = threadIdx.x;  // 128 threads
    float w = W[n * D + t];
    out_emb[n * D + t] = w;               // folded emb passthrough
    float s0 = w * w, s1 = w * aei[t], s2 = w * aej[t];
    #pragma unroll
    for (int o = 32; o > 0; o >>= 1) {
        s0 += __shfl_down(s0, o); s1 += __shfl_down(s1, o); s2 += __shfl_down(s2, o);
    }
    __shared__ float r[6];
    if ((t & 63) == 0) { int q = t >> 6; r[q * 3] = s0; r[q * 3 + 1] = s1; r[q * 3 + 2] = s2; }
    __syncthreads();
    if (t == 0) {
        inv_norm[n] = 1.0f / sqrtf(r[0] + r[3]);
        ei[n] = r[1] + r[4];
        ej[n] = r[2] + r[5];
    }
}

// ---------------- K1a: cos tile 32x32, grid 16x16=256 blocks ----------------
// identical fp32 accumulation order to prior passing rounds (k0 chunks of 32, kk inner).
__global__ __launch_bounds__(256) void k_cos(const float* __restrict__ W,
                                             const float* __restrict__ inv_norm,
                                             float* __restrict__ cosm) {
    __shared__ float la[32][33];
    __shared__ float lb[32][33];
    int j0 = blockIdx.x * 32, i0 = blockIdx.y * 32, t = threadIdx.x;
    int ix = (t & 15) * 2, jx = (t >> 4) * 2;
    float acc[2][2] = {};
    for (int k0 = 0; k0 < D; k0 += 32) {
        #pragma unroll
        for (int i = 0; i < 4; ++i) {
            int lin = t + i * 256, rl = lin & 31, kk = lin >> 5;
            la[kk][rl] = W[(size_t)(i0 + rl) * D + k0 + kk];
            lb[kk][rl] = W[(size_t)(j0 + rl) * D + k0 + kk];
        }
        __syncthreads();
        #pragma unroll
        for (int kk = 0; kk < 32; ++kk) {
            float a0 = la[kk][ix], a1 = la[kk][ix + 1];
            float b0 = lb[kk][jx], b1 = lb[kk][jx + 1];
            acc[0][0] += a0 * b0; acc[0][1] += a0 * b1;
            acc[1][0] += a1 * b0; acc[1][1] += a1 * b1;
        }
        __syncthreads();
    }
    #pragma unroll
    for (int ii = 0; ii < 2; ++ii) {
        float inv_i = inv_norm[i0 + ix + ii];
        float2 v;
        v.x = acc[ii][0] * inv_i * inv_norm[j0 + jx + 0];
        v.y = acc[ii][1] * inv_i * inv_norm[j0 + jx + 1];
        *(float2*)&cosm[(size_t)(i0 + ix + ii) * N + j0 + jx] = v;
    }
}

// ---------------- K1b: top-20 selection, wave-per-row ----------------
__global__ __launch_bounds__(256) void k_sel(const float* __restrict__ cosm,
                                             int* __restrict__ topk,
                                             float* __restrict__ out_idx) {
    int t = threadIdx.x, wid = t >> 6, lane = t & 63;
    int i = blockIdx.x * 4 + wid;
    float4 p0 = *(const float4*)&cosm[(size_t)i * N + lane * 8];
    float4 p1 = *(const float4*)&cosm[(size_t)i * N + lane * 8 + 4];
    float v[8] = {p0.x, p0.y, p0.z, p0.w, p1.x, p1.y, p1.z, p1.w};
    for (int k = 0; k < TOPK; ++k) {
        float bv = v[0]; int bc = 0;
        #pragma unroll
        for (int c = 1; c < 8; ++c) if (v[c] > bv) { bv = v[c]; bc = c; }
        int bj = lane * 8 + bc;
        #pragma unroll
        for (int o = 1; o < 64; o <<= 1) {
            float ov = __shfl_xor(bv, o);
            int  oj = __shfl_xor(bj, o);
            if (ov > bv || (ov == bv && oj < bj)) { bv = ov; bj = oj; }
        }
        if (lane == 0) {
            topk[i * TOPK + k] = bj;
            out_idx[i * TOPK + k] = (float)bj;
        }
        int oc = bj & 7; bool owner = (bj >> 3) == lane;
        #pragma unroll
        for (int c = 0; c < 8; ++c) if (owner && c == oc) v[c] = -INFINITY;
    }
}

// ---------------- transpose: data[b][f][n] f32 -> dataT[b][n][f] bf16 ----------------
__global__ __launch_bounds__(256) void k_transD(const float* __restrict__ data,
                                                short* __restrict__ dataT) {
    __shared__ float lt[32][33];
    int f0 = blockIdx.x * 32, n0 = blockIdx.y * 32, b = blockIdx.z, t = threadIdx.x;
    {
        int f = t >> 3, ng = (t & 7) * 4;
        float4 v = *(const float4*)&data[((size_t)b * F_IN + f0 + f) * N + n0 + ng];
        lt[f][ng] = v.x; lt[f][ng + 1] = v.y; lt[f][ng + 2] = v.z; lt[f][ng + 3] = v.w;
    }
    __syncthreads();
    {
        int n = t >> 3, fg = (t & 7) * 4;
        short4 w;
        w.x = f2bs(lt[fg + 0][n]); w.y = f2bs(lt[fg + 1][n]);
        w.z = f2bs(lt[fg + 2][n]); w.w = f2bs(lt[fg + 3][n]);
        *(short4*)&dataT[((size_t)b * N + n0 + n) * F_IN + f0 + fg] = w;
    }
}

// ---------------- xl: tile 64n x 128d, grid (N/64, B) = 512 blocks (2/CU) ----------------
__global__ __launch_bounds__(256) void k_xl(const short* __restrict__ dataT,
                                            const float* __restrict__ lin_w,
                                            short* __restrict__ xlb) {
    __shared__ __align__(16) short lds_a[64 * 40];
    __shared__ __align__(16) short lds_b[128 * 40];
    int n0 = blockIdx.x * 64, b = blockIdx.y, t = threadIdx.x;
    int wid = t >> 6, lane = t & 63;
    int wm = (wid & 1) * 32, wn = (wid >> 1) * 64;
    int lr = lane & 15, quad = lane >> 4;
    f32x4 acc[2][4] = {};
    const short* Asrc = dataT + ((size_t)b * N + n0) * F_IN;
    for (int k0 = 0; k0 < F_IN; k0 += 32) {
        stage_bf16<1>(lds_a, Asrc, F_IN, k0, t);
        stage_f32<2>(lds_b, lin_w, F_IN, k0, t);
        __syncthreads();
        mfma_tiles<2, 4>(lds_a, lds_b, acc, wm, wn, lr, quad);
        __syncthreads();
    }
    #pragma unroll
    for (int ms = 0; ms < 2; ++ms)
        #pragma unroll
        for (int ns = 0; ns < 4; ++ns) {
            int mb = wm + ms * 16 + quad * 4, col = wn + ns * 16 + lr;
            #pragma unroll
            for (int r = 0; r < 4; ++r)
                xlb[((size_t)b * N + n0 + mb + r) * D + col] = f2bs(acc[ms][ns][r]);
        }
}

// ---------------- K3: attention scores, wave-per-row ----------------
__global__ __launch_bounds__(256) void k_scores(const short* __restrict__ xlb,
                                                const float* __restrict__ att_i,
                                                const float* __restrict__ att_j,
                                                const float* __restrict__ ei,
                                                const float* __restrict__ ej,
                                                float* __restrict__ s_i,
                                                float* __restrict__ s_j) {
    int t = threadIdx.x, wid = t >> 6, lane = t & 63;
    int v = blockIdx.x * 4 + wid;
    int n = v & (N - 1);
    unsigned x2 = *(const unsigned*)&xlb[(size_t)v * D + lane * 2];
    float x0 = __uint_as_float((x2 & 0xFFFFu) << 16);
    float x1 = __uint_as_float(x2 & 0xFFFF0000u);
    float2 ai = *(const float2*)&att_i[lane * 2];
    float2 aj = *(const float2*)&att_j[lane * 2];
    float si = x0 * ai.x + x1 * ai.y;
    float sj = x0 * aj.x + x1 * aj.y;
    #pragma unroll
    for (int o = 32; o > 0; o >>= 1) { si += __shfl_down(si, o); sj += __shfl_down(sj, o); }
    if (lane == 0) { s_i[v] = si + ei[n]; s_j[v] = sj + ej[n]; }
}

// ---------------- K4: softmax(20) + aggregate + BN/ReLU/gate -> Gt[b][d][n] bf16 -----
__global__ __launch_bounds__(256) void k_attn2(const short* __restrict__ xlb,
                                               const float* __restrict__ emb,
                                               const int* __restrict__ topk,
                                               const float* __restrict__ s_i,
                                               const float* __restrict__ s_j,
                                               const float* __restrict__ gnn_bias,
                                               const float* __restrict__ bn_gamma,
                                               const float* __restrict__ bn_beta,
                                               short* __restrict__ Gt) {
    __shared__ float alph[16][20];
    __shared__ int   js[16][20];
    __shared__ float lt[16][129];
    int n0 = blockIdx.x * 16, b = blockIdx.y, t = threadIdx.x;
    for (int e = t; e < 16 * TOPK; e += 256) {
        int nl = e / TOPK, k = e - nl * TOPK;
        int j = topk[(n0 + nl) * TOPK + k];
        js[nl][k] = j;
        float al = s_i[b * N + n0 + nl] + s_j[b * N + j];
        alph[nl][k] = al >= 0.f ? al : 0.2f * al;
    }
    __syncthreads();
    if (t < 16) {
        float m = -INFINITY;
        for (int k = 0; k < TOPK; ++k) m = fmaxf(m, alph[t][k]);
        float s = 0.f;
        for (int k = 0; k < TOPK; ++k) { float e_ = expf(alph[t][k] - m); alph[t][k] = e_; s += e_; }
        float inv = 1.0f / s;
        for (int k = 0; k < TOPK; ++k) alph[t][k] *= inv;
    }
    __syncthreads();
    {
        int nl = t >> 4, dl = (t & 15) * 8;
        float a[8] = {};
        for (int k = 0; k < TOPK; ++k) {
            float w = alph[nl][k];
            short8_t xv = *(const short8_t*)&xlb[((size_t)b * N + js[nl][k]) * D + dl];
            #pragma unroll
            for (int c = 0; c < 8; ++c) a[c] += w * bs2f(xv[c]);
        }
        const float bnk = 0.9999950000374997f;  // 1/sqrt(1+1e-5)
        #pragma unroll
        for (int c = 0; c < 8; ++c) {
            int d = dl + c;
            float h = (a[c] + gnn_bias[d]) * (bn_gamma[d] * bnk) + bn_beta[d];
            h = fmaxf(h, 0.f);
            lt[nl][d] = h * emb[(n0 + nl) * D + d];
        }
    }
    __syncthreads();
    {
        int d = t >> 1, half = t & 1;
        short8_t v;
        #pragma unroll
        for (int j = 0; j < 8; ++j) v[j] = f2bs(lt[half * 8 + j][d]);
        *(short8_t*)&Gt[((size_t)b * D + d) * N + n0 + half * 8] = v;
    }
}

// ---------------- gemm1: tile 128d x 64h, grid (HID/64, B) = 512 blocks ----------------
__global__ __launch_bounds__(256) void k_gemm1(const short* __restrict__ Gt,
                                               const float* __restrict__ w1,
                                               short* __restrict__ out1) {
    __shared__ __align__(16) short lds_a[128 * 40];
    __shared__ __align__(16) short lds_b[64 * 40];
    int h0 = blockIdx.x * 64, b = blockIdx.y, t = threadIdx.x;
    int wid = t >> 6, lane = t & 63;
    int wm = (wid >> 1) * 64, wn = (wid & 1) * 32;
    int lr = lane & 15, quad = lane >> 4;
    f32x4 acc[4][2] = {};
    const short* Asrc = Gt + (size_t)b * D * N;
    const float* Bsrc = w1 + (size_t)h0 * N;
    for (int k0 = 0; k0 < N; k0 += 32) {
        stage_bf16<2>(lds_a, Asrc, N, k0, t);
        stage_f32<1>(lds_b, Bsrc, N, k0, t);
        __syncthreads();
        mfma_tiles<4, 2>(lds_a, lds_b, acc, wm, wn, lr, quad);
        __syncthreads();
    }
    #pragma unroll
    for (int ms = 0; ms < 4; ++ms)
        #pragma unroll
        for (int ns = 0; ns < 2; ++ns) {
            int mb = wm + ms * 16 + quad * 4, col = h0 + wn + ns * 16 + lr;
            #pragma unroll
            for (int r = 0; r < 4; ++r)
                out1[((size_t)b * D + mb + r) * HID + col] = f2bs(acc[ms][ns][r]);
        }
}

// ---------------- gemm2: tile 128d x 64h, grid (HID/64, B) = 512 blocks ----------------
__global__ __launch_bounds__(256) void k_gemm2(const short* __restrict__ out1,
                                               const float* __restrict__ w2,
                                               const float* __restrict__ b2,
                                               float* __restrict__ out) {
    __shared__ __align__(16) short lds_a[128 * 40];
    __shared__ __align__(16) short lds_b[64 * 40];
    int h0 = blockIdx.x * 64, b = blockIdx.y, t = threadIdx.x;
    int wid = t >> 6, lane = t & 63;
    int wm = (wid >> 1) * 64, wn = (wid & 1) * 32;
    int lr = lane & 15, quad = lane >> 4;
    f32x4 acc[4][2] = {};
    const short* Asrc = out1 + (size_t)b * D * HID;
    const float* Bsrc = w2 + (size_t)h0 * HID;
    for (int k0 = 0; k0 < HID; k0 += 32) {
        stage_bf16<2>(lds_a, Asrc, HID, k0, t);
        stage_f32<1>(lds_b, Bsrc, HID, k0, t);
        __syncthreads();
        mfma_tiles<4, 2>(lds_a, lds_b, acc, wm, wn, lr, quad);
        __syncthreads();
    }
    #pragma unroll
    for (int ms = 0; ms < 4; ++ms)
        #pragma unroll
        for (int ns = 0; ns < 2; ++ns) {
            int mb = wm + ms * 16 + quad * 4, col = h0 + wn + ns * 16 + lr;
            float bias = b2[col];
            #pragma unroll
            for (int r = 0; r < 4; ++r)
                out[((size_t)b * D + mb + r) * HID + col] =
                    1.0f / (1.0f + expf(-(acc[ms][ns][r] + bias)));
        }
}

extern "C" void kernel_launch(void* const* d_in, const int* in_sizes, int n_in,
                              void* d_out, int out_size, void* d_ws, size_t ws_size,
                              hipStream_t stream) {
    const float* data     = (const float*)d_in[0];
    const float* emb      = (const float*)d_in[1];
    const float* lin_w    = (const float*)d_in[2];
    const float* att_i    = (const float*)d_in[3];
    const float* att_j    = (const float*)d_in[4];
    const float* att_em_i = (const float*)d_in[5];
    const float* att_em_j = (const float*)d_in[6];
    const float* gnn_bias = (const float*)d_in[7];
    const float* bn_gamma = (const float*)d_in[8];
    const float* bn_beta  = (const float*)d_in[9];
    const float* w1       = (const float*)d_in[10];
    const float* w2       = (const float*)d_in[11];
    const float* b2       = (const float*)d_in[12];
    float* out            = (float*)d_out;   // f32 outputs: [out | emb | topk_idx]

    float* ws       = (float*)d_ws;
    float* inv_norm = ws;                                  // 512 f32
    float* ei       = ws + 512;                            // 512 f32
    float* ej       = ws + 1024;                           // 512 f32
    int*   topk     = (int*)(ws + 1536);                   // 10240 i32
    float* s_i      = ws + 1536 + N * TOPK;                // 32768 f32
    float* s_j      = s_i + B * N;                         // 32768 f32
    short* dataT    = (short*)(ws + 77312);                // B*N*F_IN bf16 = 16 MB (16B aligned)
    float* cosm     = (float*)dataT;                       // 1 MB, dead before transD writes dataT
    short* Gt       = dataT;                               // B*D*N bf16 = 8 MB (dataT dead)
    short* out1     = dataT + (size_t)B * D * N;           // B*D*HID bf16 = 8 MB
    short* xlb      = dataT + (size_t)B * N * F_IN;        // B*N*D bf16 = 8 MB

    float* out_emb = out + (size_t)B * D * HID;
    float* out_idx = out_emb + (size_t)N * D;

    hipLaunchKernelGGL(k_norm,   dim3(N),              dim3(D),   0, stream, emb, att_em_i, att_em_j, inv_norm, ei, ej, out_emb);
    hipLaunchKernelGGL(k_cos,    dim3(N / 32, N / 32), dim3(256), 0, stream, emb, inv_norm, cosm);
    hipLaunchKernelGGL(k_sel,    dim3(N / 4),          dim3(256), 0, stream, cosm, topk, out_idx);
    hipLaunchKernelGGL(k_transD, dim3(F_IN / 32, N / 32, B), dim3(256), 0, stream, data, dataT);
    hipLaunchKernelGGL(k_xl,     dim3(N / 64, B),      dim3(256), 0, stream, dataT, lin_w, xlb);
    hipLaunchKernelGGL(k_scores, dim3(B * N / 4),      dim3(256), 0, stream, xlb, att_i, att_j, ei, ej, s_i, s_j);
    hipLaunchKernelGGL(k_attn2,  dim3(N / 16, B),      dim3(256), 0, stream, xlb, emb, topk, s_i, s_j, gnn_bias, bn_gamma, bn_beta, Gt);
    hipLaunchKernelGGL(k_gemm1,  dim3(HID / 64, B),    dim3(256), 0, stream, Gt, w1, out1);
    hipLaunchKernelGGL(k_gemm2,  dim3(HID / 64, B),    dim3(256), 0, stream, out1, w2, b2, out);
}

// Round 7
// 189.782 us; speedup vs baseline: 2.4993x; 1.0589x over previous
//
#include <hip/hip_runtime.h>
#include <hip/hip_bf16.h>

constexpr int B = 64, N = 512, F_IN = 256, D = 128, TOPK = 20, HID = 512;

typedef __attribute__((ext_vector_type(8))) short short8_t;   // 8 bf16 = one MFMA frag (4 VGPRs)
typedef __attribute__((ext_vector_type(4))) float f32x4;      // MFMA C/D frag

__device__ inline short f2bs(float f) {   // f32 -> bf16 bits (RNE)
    union { __hip_bfloat16 h; short s; } u; u.h = __float2bfloat16(f); return u.s;
}
__device__ inline float bs2f(short s) {   // bf16 bits -> f32 (shift)
    return __uint_as_float(((unsigned)(unsigned short)s) << 16);
}

// stage ROWS x 32 bf16 tile into LDS (stride 40 shorts); ITERS = ROWS/64
template<int ITERS>
__device__ inline void stage_bf16(short* ldst, const short* __restrict__ src,
                                  int stride, int k0, int t) {
    #pragma unroll
    for (int i = 0; i < ITERS; ++i) {
        int lin = t + i * 256, row = lin >> 2, seg = lin & 3;
        *(short8_t*)&ldst[row * 40 + seg * 8] =
            *(const short8_t*)&src[(size_t)row * stride + k0 + seg * 8];
    }
}
template<int ITERS>
__device__ inline void stage_f32(short* ldst, const float* __restrict__ src,
                                 int stride, int k0, int t) {
    #pragma unroll
    for (int i = 0; i < ITERS; ++i) {
        int lin = t + i * 256, row = lin >> 2, seg = lin & 3;
        const float* p = &src[(size_t)row * stride + k0 + seg * 8];
        float4 x = *(const float4*)p, y = *(const float4*)(p + 4);
        short8_t v = { f2bs(x.x), f2bs(x.y), f2bs(x.z), f2bs(x.w),
                       f2bs(y.x), f2bs(y.y), f2bs(y.z), f2bs(y.w) };
        *(short8_t*)&ldst[row * 40 + seg * 8] = v;
    }
}

// MS x NS grid of 16x16x32 MFMAs from staged LDS tiles
template<int MS, int NS>
__device__ inline void mfma_tiles(const short* lds_a, const short* lds_b,
                                  f32x4 (&acc)[MS][NS], int wm, int wn, int lr, int quad) {
    short8_t af[MS], bf[NS];
    #pragma unroll
    for (int ms = 0; ms < MS; ++ms)
        af[ms] = *(const short8_t*)&lds_a[(wm + ms * 16 + lr) * 40 + quad * 8];
    #pragma unroll
    for (int ns = 0; ns < NS; ++ns)
        bf[ns] = *(const short8_t*)&lds_b[(wn + ns * 16 + lr) * 40 + quad * 8];
    #pragma unroll
    for (int ms = 0; ms < MS; ++ms)
        #pragma unroll
        for (int ns = 0; ns < NS; ++ns)
            acc[ms][ns] = __builtin_amdgcn_mfma_f32_16x16x32_bf16(af[ms], bf[ns], acc[ms][ns], 0, 0, 0);
}

// ---------------- K0: row norms + att_em dots + emb passthrough copy ----------------
__global__ void k_norm(const float* __restrict__ W, const float* __restrict__ aei,
                       const float* __restrict__ aej, float* __restrict__ inv_norm,
                       float* __restrict__ ei, float* __restrict__ ej,
                       float* __restrict__ out_emb) {
    int n = blockIdx.x, t = threadIdx.x;  // 128 threads
    float w = W[n * D + t];
    out_emb[n * D + t] = w;               // folded emb passthrough
    float s0 = w * w, s1 = w * aei[t], s2 = w * aej[t];
    #pragma unroll
    for (int o = 32; o > 0; o >>= 1) {
        s0 += __shfl_down(s0, o); s1 += __shfl_down(s1, o); s2 += __shfl_down(s2, o);
    }
    __shared__ float r[6];
    if ((t & 63) == 0) { int q = t >> 6; r[q * 3] = s0; r[q * 3 + 1] = s1; r[q * 3 + 2] = s2; }
    __syncthreads();
    if (t == 0) {
        inv_norm[n] = 1.0f / sqrtf(r[0] + r[3]);
        ei[n] = r[1] + r[4];
        ej[n] = r[2] + r[5];
    }
}

// ---------------- K1a: cos tile 32x32, grid 16x16=256 blocks ----------------
__global__ __launch_bounds__(256) void k_cos(const float* __restrict__ W,
                                             const float* __restrict__ inv_norm,
                                             float* __restrict__ cosm) {
    __shared__ float la[32][33];
    __shared__ float lb[32][33];
    int j0 = blockIdx.x * 32, i0 = blockIdx.y * 32, t = threadIdx.x;
    int ix = (t & 15) * 2, jx = (t >> 4) * 2;
    float acc[2][2] = {};
    for (int k0 = 0; k0 < D; k0 += 32) {
        #pragma unroll
        for (int i = 0; i < 4; ++i) {
            int lin = t + i * 256, rl = lin & 31, kk = lin >> 5;
            la[kk][rl] = W[(size_t)(i0 + rl) * D + k0 + kk];
            lb[kk][rl] = W[(size_t)(j0 + rl) * D + k0 + kk];
        }
        __syncthreads();
        #pragma unroll
        for (int kk = 0; kk < 32; ++kk) {
            float a0 = la[kk][ix], a1 = la[kk][ix + 1];
            float b0 = lb[kk][jx], b1 = lb[kk][jx + 1];
            acc[0][0] += a0 * b0; acc[0][1] += a0 * b1;
            acc[1][0] += a1 * b0; acc[1][1] += a1 * b1;
        }
        __syncthreads();
    }
    #pragma unroll
    for (int ii = 0; ii < 2; ++ii) {
        float inv_i = inv_norm[i0 + ix + ii];
        float2 v;
        v.x = acc[ii][0] * inv_i * inv_norm[j0 + jx + 0];
        v.y = acc[ii][1] * inv_i * inv_norm[j0 + jx + 1];
        *(float2*)&cosm[(size_t)(i0 + ix + ii) * N + j0 + jx] = v;
    }
}

// ---------------- K1b: top-20 selection, wave-per-row ----------------
__global__ __launch_bounds__(256) void k_sel(const float* __restrict__ cosm,
                                             int* __restrict__ topk,
                                             float* __restrict__ out_idx) {
    int t = threadIdx.x, wid = t >> 6, lane = t & 63;
    int i = blockIdx.x * 4 + wid;
    float4 p0 = *(const float4*)&cosm[(size_t)i * N + lane * 8];
    float4 p1 = *(const float4*)&cosm[(size_t)i * N + lane * 8 + 4];
    float v[8] = {p0.x, p0.y, p0.z, p0.w, p1.x, p1.y, p1.z, p1.w};
    for (int k = 0; k < TOPK; ++k) {
        float bv = v[0]; int bc = 0;
        #pragma unroll
        for (int c = 1; c < 8; ++c) if (v[c] > bv) { bv = v[c]; bc = c; }
        int bj = lane * 8 + bc;
        #pragma unroll
        for (int o = 1; o < 64; o <<= 1) {
            float ov = __shfl_xor(bv, o);
            int  oj = __shfl_xor(bj, o);
            if (ov > bv || (ov == bv && oj < bj)) { bv = ov; bj = oj; }
        }
        if (lane == 0) {
            topk[i * TOPK + k] = bj;
            out_idx[i * TOPK + k] = (float)bj;
        }
        int oc = bj & 7; bool owner = (bj >> 3) == lane;
        #pragma unroll
        for (int c = 0; c < 8; ++c) if (owner && c == oc) v[c] = -INFINITY;
    }
}

// ---------------- xl (fused transpose + scores): tile 64n x 128d, grid (N/64, B) -------
// A-tile comes straight from data[b][f][n] via an LDS f32 transpose tile (stride 65:
// write banks 2-way, column reads 2-way — both free). Epilogue computes s_i/s_j from
// the f32 accumulators (replaces k_scores).
__global__ __launch_bounds__(256) void k_xl(const float* __restrict__ data,
                                            const float* __restrict__ lin_w,
                                            const float* __restrict__ att_i,
                                            const float* __restrict__ att_j,
                                            const float* __restrict__ ei,
                                            const float* __restrict__ ej,
                                            short* __restrict__ xlb,
                                            float* __restrict__ s_i,
                                            float* __restrict__ s_j) {
    __shared__ float lt[32][65];                       // f32 transpose staging [f][n]
    __shared__ __align__(16) short lds_a[64 * 40];
    __shared__ __align__(16) short lds_b[128 * 40];
    __shared__ float sred[2][64][2];
    int n0 = blockIdx.x * 64, b = blockIdx.y, t = threadIdx.x;
    int wid = t >> 6, lane = t & 63;
    int wm = (wid & 1) * 32, wn = (wid >> 1) * 64;
    int lr = lane & 15, quad = lane >> 4;
    f32x4 acc[2][4] = {};
    for (int k0 = 0; k0 < F_IN; k0 += 32) {
        {   // load 32f x 64n tile of data, coalesced along n
            int f = t >> 3, ng = (t & 7) * 8;
            const float* p = &data[((size_t)b * F_IN + k0 + f) * N + n0 + ng];
            float4 v0 = *(const float4*)p, v1 = *(const float4*)(p + 4);
            float* q = &lt[f][ng];
            q[0] = v0.x; q[1] = v0.y; q[2] = v0.z; q[3] = v0.w;
            q[4] = v1.x; q[5] = v1.y; q[6] = v1.z; q[7] = v1.w;
        }
        stage_f32<2>(lds_b, lin_w, F_IN, k0, t);
        __syncthreads();
        {   // repack transposed: lds_a[n][f] bf16 fragments
            int row = t >> 2, seg = t & 3;
            short8_t a;
            #pragma unroll
            for (int j = 0; j < 8; ++j) a[j] = f2bs(lt[seg * 8 + j][row]);
            *(short8_t*)&lds_a[row * 40 + seg * 8] = a;
        }
        __syncthreads();
        mfma_tiles<2, 4>(lds_a, lds_b, acc, wm, wn, lr, quad);
        __syncthreads();
    }
    // store xl (bf16)
    #pragma unroll
    for (int ms = 0; ms < 2; ++ms)
        #pragma unroll
        for (int ns = 0; ns < 4; ++ns) {
            int mb = wm + ms * 16 + quad * 4, col = wn + ns * 16 + lr;
            #pragma unroll
            for (int r = 0; r < 4; ++r)
                xlb[((size_t)b * N + n0 + mb + r) * D + col] = f2bs(acc[ms][ns][r]);
        }
    // fused attention scores from f32 accumulators
    float si8[8], sj8[8];
    #pragma unroll
    for (int ms = 0; ms < 2; ++ms)
        #pragma unroll
        for (int r = 0; r < 4; ++r) {
            float si = 0.f, sj = 0.f;
            #pragma unroll
            for (int ns = 0; ns < 4; ++ns) {
                int col = wn + ns * 16 + lr;
                float x = acc[ms][ns][r];
                si += x * att_i[col];
                sj += x * att_j[col];
            }
            si8[ms * 4 + r] = si; sj8[ms * 4 + r] = sj;
        }
    #pragma unroll
    for (int o = 1; o < 16; o <<= 1) {
        #pragma unroll
        for (int i = 0; i < 8; ++i) {
            si8[i] += __shfl_xor(si8[i], o);
            sj8[i] += __shfl_xor(sj8[i], o);
        }
    }
    if (lr == 0) {
        #pragma unroll
        for (int ms = 0; ms < 2; ++ms)
            #pragma unroll
            for (int r = 0; r < 4; ++r) {
                int row = wm + ms * 16 + quad * 4 + r;
                sred[wid >> 1][row][0] = si8[ms * 4 + r];
                sred[wid >> 1][row][1] = sj8[ms * 4 + r];
            }
    }
    __syncthreads();
    if (t < 64) {
        int n = n0 + t;
        s_i[b * N + n] = sred[0][t][0] + sred[1][t][0] + ei[n];
        s_j[b * N + n] = sred[0][t][1] + sred[1][t][1] + ej[n];
    }
}

// ---------------- K4: softmax(20) + aggregate + BN/ReLU/gate -> Gt[b][d][n] bf16 -----
__global__ __launch_bounds__(256) void k_attn2(const short* __restrict__ xlb,
                                               const float* __restrict__ emb,
                                               const int* __restrict__ topk,
                                               const float* __restrict__ s_i,
                                               const float* __restrict__ s_j,
                                               const float* __restrict__ gnn_bias,
                                               const float* __restrict__ bn_gamma,
                                               const float* __restrict__ bn_beta,
                                               short* __restrict__ Gt) {
    __shared__ float alph[16][20];
    __shared__ int   js[16][20];
    __shared__ float lt[16][129];
    int n0 = blockIdx.x * 16, b = blockIdx.y, t = threadIdx.x;
    for (int e = t; e < 16 * TOPK; e += 256) {
        int nl = e / TOPK, k = e - nl * TOPK;
        int j = topk[(n0 + nl) * TOPK + k];
        js[nl][k] = j;
        float al = s_i[b * N + n0 + nl] + s_j[b * N + j];
        alph[nl][k] = al >= 0.f ? al : 0.2f * al;
    }
    __syncthreads();
    if (t < 16) {
        float m = -INFINITY;
        for (int k = 0; k < TOPK; ++k) m = fmaxf(m, alph[t][k]);
        float s = 0.f;
        for (int k = 0; k < TOPK; ++k) { float e_ = expf(alph[t][k] - m); alph[t][k] = e_; s += e_; }
        float inv = 1.0f / s;
        for (int k = 0; k < TOPK; ++k) alph[t][k] *= inv;
    }
    __syncthreads();
    {
        int nl = t >> 4, dl = (t & 15) * 8;
        float a[8] = {};
        for (int k = 0; k < TOPK; ++k) {
            float w = alph[nl][k];
            short8_t xv = *(const short8_t*)&xlb[((size_t)b * N + js[nl][k]) * D + dl];
            #pragma unroll
            for (int c = 0; c < 8; ++c) a[c] += w * bs2f(xv[c]);
        }
        const float bnk = 0.9999950000374997f;  // 1/sqrt(1+1e-5)
        #pragma unroll
        for (int c = 0; c < 8; ++c) {
            int d = dl + c;
            float h = (a[c] + gnn_bias[d]) * (bn_gamma[d] * bnk) + bn_beta[d];
            h = fmaxf(h, 0.f);
            lt[nl][d] = h * emb[(n0 + nl) * D + d];
        }
    }
    __syncthreads();
    {
        int d = t >> 1, half = t & 1;
        short8_t v;
        #pragma unroll
        for (int j = 0; j < 8; ++j) v[j] = f2bs(lt[half * 8 + j][d]);
        *(short8_t*)&Gt[((size_t)b * D + d) * N + n0 + half * 8] = v;
    }
}

// ---------------- gemm1: tile 128d x 64h, grid (HID/64, B) = 512 blocks ----------------
__global__ __launch_bounds__(256) void k_gemm1(const short* __restrict__ Gt,
                                               const float* __restrict__ w1,
                                               short* __restrict__ out1) {
    __shared__ __align__(16) short lds_a[128 * 40];
    __shared__ __align__(16) short lds_b[64 * 40];
    int h0 = blockIdx.x * 64, b = blockIdx.y, t = threadIdx.x;
    int wid = t >> 6, lane = t & 63;
    int wm = (wid >> 1) * 64, wn = (wid & 1) * 32;
    int lr = lane & 15, quad = lane >> 4;
    f32x4 acc[4][2] = {};
    const short* Asrc = Gt + (size_t)b * D * N;
    const float* Bsrc = w1 + (size_t)h0 * N;
    for (int k0 = 0; k0 < N; k0 += 32) {
        stage_bf16<2>(lds_a, Asrc, N, k0, t);
        stage_f32<1>(lds_b, Bsrc, N, k0, t);
        __syncthreads();
        mfma_tiles<4, 2>(lds_a, lds_b, acc, wm, wn, lr, quad);
        __syncthreads();
    }
    #pragma unroll
    for (int ms = 0; ms < 4; ++ms)
        #pragma unroll
        for (int ns = 0; ns < 2; ++ns) {
            int mb = wm + ms * 16 + quad * 4, col = h0 + wn + ns * 16 + lr;
            #pragma unroll
            for (int r = 0; r < 4; ++r)
                out1[((size_t)b * D + mb + r) * HID + col] = f2bs(acc[ms][ns][r]);
        }
}

// ---------------- gemm2: tile 128d x 64h, grid (HID/64, B) = 512 blocks ----------------
__global__ __launch_bounds__(256) void k_gemm2(const short* __restrict__ out1,
                                               const float* __restrict__ w2,
                                               const float* __restrict__ b2,
                                               float* __restrict__ out) {
    __shared__ __align__(16) short lds_a[128 * 40];
    __shared__ __align__(16) short lds_b[64 * 40];
    int h0 = blockIdx.x * 64, b = blockIdx.y, t = threadIdx.x;
    int wid = t >> 6, lane = t & 63;
    int wm = (wid >> 1) * 64, wn = (wid & 1) * 32;
    int lr = lane & 15, quad = lane >> 4;
    f32x4 acc[4][2] = {};
    const short* Asrc = out1 + (size_t)b * D * HID;
    const float* Bsrc = w2 + (size_t)h0 * HID;
    for (int k0 = 0; k0 < HID; k0 += 32) {
        stage_bf16<2>(lds_a, Asrc, HID, k0, t);
        stage_f32<1>(lds_b, Bsrc, HID, k0, t);
        __syncthreads();
        mfma_tiles<4, 2>(lds_a, lds_b, acc, wm, wn, lr, quad);
        __syncthreads();
    }
    #pragma unroll
    for (int ms = 0; ms < 4; ++ms)
        #pragma unroll
        for (int ns = 0; ns < 2; ++ns) {
            int mb = wm + ms * 16 + quad * 4, col = h0 + wn + ns * 16 + lr;
            float bias = b2[col];
            #pragma unroll
            for (int r = 0; r < 4; ++r)
                out[((size_t)b * D + mb + r) * HID + col] =
                    1.0f / (1.0f + expf(-(acc[ms][ns][r] + bias)));
        }
}

extern "C" void kernel_launch(void* const* d_in, const int* in_sizes, int n_in,
                              void* d_out, int out_size, void* d_ws, size_t ws_size,
                              hipStream_t stream) {
    const float* data     = (const float*)d_in[0];
    const float* emb      = (const float*)d_in[1];
    const float* lin_w    = (const float*)d_in[2];
    const float* att_i    = (const float*)d_in[3];
    const float* att_j    = (const float*)d_in[4];
    const float* att_em_i = (const float*)d_in[5];
    const float* att_em_j = (const float*)d_in[6];
    const float* gnn_bias = (const float*)d_in[7];
    const float* bn_gamma = (const float*)d_in[8];
    const float* bn_beta  = (const float*)d_in[9];
    const float* w1       = (const float*)d_in[10];
    const float* w2       = (const float*)d_in[11];
    const float* b2       = (const float*)d_in[12];
    float* out            = (float*)d_out;   // f32 outputs: [out | emb | topk_idx]

    float* ws       = (float*)d_ws;
    float* inv_norm = ws;                                  // 512 f32
    float* ei       = ws + 512;                            // 512 f32
    float* ej       = ws + 1024;                           // 512 f32
    int*   topk     = (int*)(ws + 1536);                   // 10240 i32
    float* s_i      = ws + 1536 + N * TOPK;                // 32768 f32
    float* s_j      = s_i + B * N;                         // 32768 f32
    short* S        = (short*)(ws + 77312);                // 24 MB region (16B aligned)
    short* Gt       = S;                                   // B*D*N bf16 = 8 MB
    short* out1     = S + (size_t)B * D * N;               // 8 MB
    short* xlb      = S + 2 * (size_t)B * D * N;           // 8 MB
    float* cosm     = (float*)S;                           // 1 MB, dead before attn2 writes Gt

    float* out_emb = out + (size_t)B * D * HID;
    float* out_idx = out_emb + (size_t)N * D;

    hipLaunchKernelGGL(k_norm,  dim3(N),              dim3(D),   0, stream, emb, att_em_i, att_em_j, inv_norm, ei, ej, out_emb);
    hipLaunchKernelGGL(k_cos,   dim3(N / 32, N / 32), dim3(256), 0, stream, emb, inv_norm, cosm);
    hipLaunchKernelGGL(k_sel,   dim3(N / 4),          dim3(256), 0, stream, cosm, topk, out_idx);
    hipLaunchKernelGGL(k_xl,    dim3(N / 64, B),      dim3(256), 0, stream, data, lin_w, att_i, att_j, ei, ej, xlb, s_i, s_j);
    hipLaunchKernelGGL(k_attn2, dim3(N / 16, B),      dim3(256), 0, stream, xlb, emb, topk, s_i, s_j, gnn_bias, bn_gamma, bn_beta, Gt);
    hipLaunchKernelGGL(k_gemm1, dim3(HID / 64, B),    dim3(256), 0, stream, Gt, w1, out1);
    hipLaunchKernelGGL(k_gemm2, dim3(HID / 64, B),    dim3(256), 0, stream, out1, w2, b2, out);
}

// Round 8
// 189.186 us; speedup vs baseline: 2.5071x; 1.0031x over previous
//
#include <hip/hip_runtime.h>
#include <hip/hip_bf16.h>

constexpr int B = 64, N = 512, F_IN = 256, D = 128, TOPK = 20, HID = 512;

typedef __attribute__((ext_vector_type(8))) short short8_t;   // 8 bf16 = one MFMA frag (4 VGPRs)
typedef __attribute__((ext_vector_type(4))) float f32x4;      // MFMA C/D frag

__device__ inline short f2bs(float f) {   // f32 -> bf16 bits (RNE)
    union { __hip_bfloat16 h; short s; } u; u.h = __float2bfloat16(f); return u.s;
}
__device__ inline float bs2f(short s) {   // bf16 bits -> f32 (shift)
    return __uint_as_float(((unsigned)(unsigned short)s) << 16);
}

// ---- BK=64 staging: tile ROWS x 64 bf16, LDS row stride 72 shorts (144B) ----
// ITERS = ROWS/32 (256 threads x 8 shorts = 2048 shorts = 32 rows per iter)
template<int ITERS>
__device__ inline void stage64_bf16(short* ldst, const short* __restrict__ src,
                                    int stride, int k0, int t) {
    #pragma unroll
    for (int i = 0; i < ITERS; ++i) {
        int lin = t + i * 256, row = lin >> 3, seg = lin & 7;
        *(short8_t*)&ldst[row * 72 + seg * 8] =
            *(const short8_t*)&src[(size_t)row * stride + k0 + seg * 8];
    }
}
template<int ITERS>
__device__ inline void stage64_f32(short* ldst, const float* __restrict__ src,
                                   int stride, int k0, int t) {
    #pragma unroll
    for (int i = 0; i < ITERS; ++i) {
        int lin = t + i * 256, row = lin >> 3, seg = lin & 7;
        const float* p = &src[(size_t)row * stride + k0 + seg * 8];
        float4 x = *(const float4*)p, y = *(const float4*)(p + 4);
        short8_t v = { f2bs(x.x), f2bs(x.y), f2bs(x.z), f2bs(x.w),
                       f2bs(y.x), f2bs(y.y), f2bs(y.z), f2bs(y.w) };
        *(short8_t*)&ldst[row * 72 + seg * 8] = v;
    }
}

// MS x NS grid of 16x16x32 MFMAs over a BK=64 staged pair (k-chunks 0 then 32,
// preserving the exact k-sequential accumulation order of the BK=32 version)
template<int MS, int NS>
__device__ inline void mfma_tiles64(const short* lds_a, const short* lds_b,
                                    f32x4 (&acc)[MS][NS], int wm, int wn, int lr, int quad) {
    #pragma unroll
    for (int kc = 0; kc < 64; kc += 32) {
        short8_t af[MS], bf[NS];
        #pragma unroll
        for (int ms = 0; ms < MS; ++ms)
            af[ms] = *(const short8_t*)&lds_a[(wm + ms * 16 + lr) * 72 + kc + quad * 8];
        #pragma unroll
        for (int ns = 0; ns < NS; ++ns)
            bf[ns] = *(const short8_t*)&lds_b[(wn + ns * 16 + lr) * 72 + kc + quad * 8];
        #pragma unroll
        for (int ms = 0; ms < MS; ++ms)
            #pragma unroll
            for (int ns = 0; ns < NS; ++ns)
                acc[ms][ns] = __builtin_amdgcn_mfma_f32_16x16x32_bf16(af[ms], bf[ns], acc[ms][ns], 0, 0, 0);
    }
}

// ---------------- K0: row norms + att_em dots + emb passthrough copy ----------------
__global__ void k_norm(const float* __restrict__ W, const float* __restrict__ aei,
                       const float* __restrict__ aej, float* __restrict__ inv_norm,
                       float* __restrict__ ei, float* __restrict__ ej,
                       float* __restrict__ out_emb) {
    int n = blockIdx.x, t = threadIdx.x;  // 128 threads
    float w = W[n * D + t];
    out_emb[n * D + t] = w;               // folded emb passthrough
    float s0 = w * w, s1 = w * aei[t], s2 = w * aej[t];
    #pragma unroll
    for (int o = 32; o > 0; o >>= 1) {
        s0 += __shfl_down(s0, o); s1 += __shfl_down(s1, o); s2 += __shfl_down(s2, o);
    }
    __shared__ float r[6];
    if ((t & 63) == 0) { int q = t >> 6; r[q * 3] = s0; r[q * 3 + 1] = s1; r[q * 3 + 2] = s2; }
    __syncthreads();
    if (t == 0) {
        inv_norm[n] = 1.0f / sqrtf(r[0] + r[3]);
        ei[n] = r[1] + r[4];
        ej[n] = r[2] + r[5];
    }
}

// ---------------- K1a: cos tile 32x32, grid 16x16=256 blocks ----------------
__global__ __launch_bounds__(256) void k_cos(const float* __restrict__ W,
                                             const float* __restrict__ inv_norm,
                                             float* __restrict__ cosm) {
    __shared__ float la[32][33];
    __shared__ float lb[32][33];
    int j0 = blockIdx.x * 32, i0 = blockIdx.y * 32, t = threadIdx.x;
    int ix = (t & 15) * 2, jx = (t >> 4) * 2;
    float acc[2][2] = {};
    for (int k0 = 0; k0 < D; k0 += 32) {
        #pragma unroll
        for (int i = 0; i < 4; ++i) {
            int lin = t + i * 256, rl = lin & 31, kk = lin >> 5;
            la[kk][rl] = W[(size_t)(i0 + rl) * D + k0 + kk];
            lb[kk][rl] = W[(size_t)(j0 + rl) * D + k0 + kk];
        }
        __syncthreads();
        #pragma unroll
        for (int kk = 0; kk < 32; ++kk) {
            float a0 = la[kk][ix], a1 = la[kk][ix + 1];
            float b0 = lb[kk][jx], b1 = lb[kk][jx + 1];
            acc[0][0] += a0 * b0; acc[0][1] += a0 * b1;
            acc[1][0] += a1 * b0; acc[1][1] += a1 * b1;
        }
        __syncthreads();
    }
    #pragma unroll
    for (int ii = 0; ii < 2; ++ii) {
        float inv_i = inv_norm[i0 + ix + ii];
        float2 v;
        v.x = acc[ii][0] * inv_i * inv_norm[j0 + jx + 0];
        v.y = acc[ii][1] * inv_i * inv_norm[j0 + jx + 1];
        *(float2*)&cosm[(size_t)(i0 + ix + ii) * N + j0 + jx] = v;
    }
}

// ---------------- K1b: top-20 selection, wave-per-row ----------------
__global__ __launch_bounds__(256) void k_sel(const float* __restrict__ cosm,
                                             int* __restrict__ topk,
                                             float* __restrict__ out_idx) {
    int t = threadIdx.x, wid = t >> 6, lane = t & 63;
    int i = blockIdx.x * 4 + wid;
    float4 p0 = *(const float4*)&cosm[(size_t)i * N + lane * 8];
    float4 p1 = *(const float4*)&cosm[(size_t)i * N + lane * 8 + 4];
    float v[8] = {p0.x, p0.y, p0.z, p0.w, p1.x, p1.y, p1.z, p1.w};
    for (int k = 0; k < TOPK; ++k) {
        float bv = v[0]; int bc = 0;
        #pragma unroll
        for (int c = 1; c < 8; ++c) if (v[c] > bv) { bv = v[c]; bc = c; }
        int bj = lane * 8 + bc;
        #pragma unroll
        for (int o = 1; o < 64; o <<= 1) {
            float ov = __shfl_xor(bv, o);
            int  oj = __shfl_xor(bj, o);
            if (ov > bv || (ov == bv && oj < bj)) { bv = ov; bj = oj; }
        }
        if (lane == 0) {
            topk[i * TOPK + k] = bj;
            out_idx[i * TOPK + k] = (float)bj;
        }
        int oc = bj & 7; bool owner = (bj >> 3) == lane;
        #pragma unroll
        for (int c = 0; c < 8; ++c) if (owner && c == oc) v[c] = -INFINITY;
    }
}

// ---------------- xl (fused transpose + scores), BK=64: tile 64n x 128d ----------------
__global__ __launch_bounds__(256) void k_xl(const float* __restrict__ data,
                                            const float* __restrict__ lin_w,
                                            const float* __restrict__ att_i,
                                            const float* __restrict__ att_j,
                                            const float* __restrict__ ei,
                                            const float* __restrict__ ej,
                                            short* __restrict__ xlb,
                                            float* __restrict__ s_i,
                                            float* __restrict__ s_j) {
    __shared__ float lt[64][65];                       // f32 transpose staging [f][n]
    __shared__ __align__(16) short lds_a[64 * 72];
    __shared__ __align__(16) short lds_b[128 * 72];
    __shared__ float sred[2][64][2];
    int n0 = blockIdx.x * 64, b = blockIdx.y, t = threadIdx.x;
    int wid = t >> 6, lane = t & 63;
    int wm = (wid & 1) * 32, wn = (wid >> 1) * 64;
    int lr = lane & 15, quad = lane >> 4;
    f32x4 acc[2][4] = {};
    for (int k0 = 0; k0 < F_IN; k0 += 64) {
        #pragma unroll
        for (int i = 0; i < 2; ++i) {   // load 64f x 64n data tile, coalesced along n
            int lin = t + i * 256, f = lin >> 3, ng = (lin & 7) * 8;
            const float* p = &data[((size_t)b * F_IN + k0 + f) * N + n0 + ng];
            float4 v0 = *(const float4*)p, v1 = *(const float4*)(p + 4);
            float* q = &lt[f][ng];
            q[0] = v0.x; q[1] = v0.y; q[2] = v0.z; q[3] = v0.w;
            q[4] = v1.x; q[5] = v1.y; q[6] = v1.z; q[7] = v1.w;
        }
        stage64_f32<4>(lds_b, lin_w, F_IN, k0, t);
        __syncthreads();
        #pragma unroll
        for (int i = 0; i < 2; ++i) {   // repack transposed: lds_a[n][f] bf16
            int lin = t + i * 256, row = lin >> 3, seg = lin & 7;
            short8_t a;
            #pragma unroll
            for (int j = 0; j < 8; ++j) a[j] = f2bs(lt[seg * 8 + j][row]);
            *(short8_t*)&lds_a[row * 72 + seg * 8] = a;
        }
        __syncthreads();
        mfma_tiles64<2, 4>(lds_a, lds_b, acc, wm, wn, lr, quad);
        __syncthreads();
    }
    // store xl (bf16)
    #pragma unroll
    for (int ms = 0; ms < 2; ++ms)
        #pragma unroll
        for (int ns = 0; ns < 4; ++ns) {
            int mb = wm + ms * 16 + quad * 4, col = wn + ns * 16 + lr;
            #pragma unroll
            for (int r = 0; r < 4; ++r)
                xlb[((size_t)b * N + n0 + mb + r) * D + col] = f2bs(acc[ms][ns][r]);
        }
    // fused attention scores from f32 accumulators
    float si8[8], sj8[8];
    #pragma unroll
    for (int ms = 0; ms < 2; ++ms)
        #pragma unroll
        for (int r = 0; r < 4; ++r) {
            float si = 0.f, sj = 0.f;
            #pragma unroll
            for (int ns = 0; ns < 4; ++ns) {
                int col = wn + ns * 16 + lr;
                float x = acc[ms][ns][r];
                si += x * att_i[col];
                sj += x * att_j[col];
            }
            si8[ms * 4 + r] = si; sj8[ms * 4 + r] = sj;
        }
    #pragma unroll
    for (int o = 1; o < 16; o <<= 1) {
        #pragma unroll
        for (int i = 0; i < 8; ++i) {
            si8[i] += __shfl_xor(si8[i], o);
            sj8[i] += __shfl_xor(sj8[i], o);
        }
    }
    if (lr == 0) {
        #pragma unroll
        for (int ms = 0; ms < 2; ++ms)
            #pragma unroll
            for (int r = 0; r < 4; ++r) {
                int row = wm + ms * 16 + quad * 4 + r;
                sred[wid >> 1][row][0] = si8[ms * 4 + r];
                sred[wid >> 1][row][1] = sj8[ms * 4 + r];
            }
    }
    __syncthreads();
    if (t < 64) {
        int n = n0 + t;
        s_i[b * N + n] = sred[0][t][0] + sred[1][t][0] + ei[n];
        s_j[b * N + n] = sred[0][t][1] + sred[1][t][1] + ej[n];
    }
}

// ---------------- K4: softmax(20) + aggregate + BN/ReLU/gate -> Gt[b][d][n] bf16 -----
__global__ __launch_bounds__(256) void k_attn2(const short* __restrict__ xlb,
                                               const float* __restrict__ emb,
                                               const int* __restrict__ topk,
                                               const float* __restrict__ s_i,
                                               const float* __restrict__ s_j,
                                               const float* __restrict__ gnn_bias,
                                               const float* __restrict__ bn_gamma,
                                               const float* __restrict__ bn_beta,
                                               short* __restrict__ Gt) {
    __shared__ float alph[16][20];
    __shared__ int   js[16][20];
    __shared__ float lt[16][129];
    int n0 = blockIdx.x * 16, b = blockIdx.y, t = threadIdx.x;
    for (int e = t; e < 16 * TOPK; e += 256) {
        int nl = e / TOPK, k = e - nl * TOPK;
        int j = topk[(n0 + nl) * TOPK + k];
        js[nl][k] = j;
        float al = s_i[b * N + n0 + nl] + s_j[b * N + j];
        alph[nl][k] = al >= 0.f ? al : 0.2f * al;
    }
    __syncthreads();
    if (t < 16) {
        float m = -INFINITY;
        for (int k = 0; k < TOPK; ++k) m = fmaxf(m, alph[t][k]);
        float s = 0.f;
        for (int k = 0; k < TOPK; ++k) { float e_ = expf(alph[t][k] - m); alph[t][k] = e_; s += e_; }
        float inv = 1.0f / s;
        for (int k = 0; k < TOPK; ++k) alph[t][k] *= inv;
    }
    __syncthreads();
    {
        int nl = t >> 4, dl = (t & 15) * 8;
        float a[8] = {};
        for (int k = 0; k < TOPK; ++k) {
            float w = alph[nl][k];
            short8_t xv = *(const short8_t*)&xlb[((size_t)b * N + js[nl][k]) * D + dl];
            #pragma unroll
            for (int c = 0; c < 8; ++c) a[c] += w * bs2f(xv[c]);
        }
        const float bnk = 0.9999950000374997f;  // 1/sqrt(1+1e-5)
        #pragma unroll
        for (int c = 0; c < 8; ++c) {
            int d = dl + c;
            float h = (a[c] + gnn_bias[d]) * (bn_gamma[d] * bnk) + bn_beta[d];
            h = fmaxf(h, 0.f);
            lt[nl][d] = h * emb[(n0 + nl) * D + d];
        }
    }
    __syncthreads();
    {
        int d = t >> 1, half = t & 1;
        short8_t v;
        #pragma unroll
        for (int j = 0; j < 8; ++j) v[j] = f2bs(lt[half * 8 + j][d]);
        *(short8_t*)&Gt[((size_t)b * D + d) * N + n0 + half * 8] = v;
    }
}

// ---------------- gemm1: tile 64d x 64h, BK=64, grid (8, 2, 64) = 1024 blocks ----------
__global__ __launch_bounds__(256) void k_gemm1(const short* __restrict__ Gt,
                                               const float* __restrict__ w1,
                                               short* __restrict__ out1) {
    __shared__ __align__(16) short lds_a[64 * 72];
    __shared__ __align__(16) short lds_b[64 * 72];
    int h0 = blockIdx.x * 64, d0 = blockIdx.y * 64, b = blockIdx.z, t = threadIdx.x;
    int wid = t >> 6, lane = t & 63;
    int wm = (wid >> 1) * 32, wn = (wid & 1) * 32;
    int lr = lane & 15, quad = lane >> 4;
    f32x4 acc[2][2] = {};
    const short* Asrc = Gt + ((size_t)b * D + d0) * N;
    const float* Bsrc = w1 + (size_t)h0 * N;
    for (int k0 = 0; k0 < N; k0 += 64) {
        stage64_bf16<2>(lds_a, Asrc, N, k0, t);
        stage64_f32<2>(lds_b, Bsrc, N, k0, t);
        __syncthreads();
        mfma_tiles64<2, 2>(lds_a, lds_b, acc, wm, wn, lr, quad);
        __syncthreads();
    }
    #pragma unroll
    for (int ms = 0; ms < 2; ++ms)
        #pragma unroll
        for (int ns = 0; ns < 2; ++ns) {
            int mb = d0 + wm + ms * 16 + quad * 4, col = h0 + wn + ns * 16 + lr;
            #pragma unroll
            for (int r = 0; r < 4; ++r)
                out1[((size_t)b * D + mb + r) * HID + col] = f2bs(acc[ms][ns][r]);
        }
}

// ---------------- gemm2: tile 64d x 64h, BK=64, grid (8, 2, 64) = 1024 blocks ----------
__global__ __launch_bounds__(256) void k_gemm2(const short* __restrict__ out1,
                                               const float* __restrict__ w2,
                                               const float* __restrict__ b2,
                                               float* __restrict__ out) {
    __shared__ __align__(16) short lds_a[64 * 72];
    __shared__ __align__(16) short lds_b[64 * 72];
    int h0 = blockIdx.x * 64, d0 = blockIdx.y * 64, b = blockIdx.z, t = threadIdx.x;
    int wid = t >> 6, lane = t & 63;
    int wm = (wid >> 1) * 32, wn = (wid & 1) * 32;
    int lr = lane & 15, quad = lane >> 4;
    f32x4 acc[2][2] = {};
    const short* Asrc = out1 + ((size_t)b * D + d0) * HID;
    const float* Bsrc = w2 + (size_t)h0 * HID;
    for (int k0 = 0; k0 < HID; k0 += 64) {
        stage64_bf16<2>(lds_a, Asrc, HID, k0, t);
        stage64_f32<2>(lds_b, Bsrc, HID, k0, t);
        __syncthreads();
        mfma_tiles64<2, 2>(lds_a, lds_b, acc, wm, wn, lr, quad);
        __syncthreads();
    }
    #pragma unroll
    for (int ms = 0; ms < 2; ++ms)
        #pragma unroll
        for (int ns = 0; ns < 2; ++ns) {
            int mb = d0 + wm + ms * 16 + quad * 4, col = h0 + wn + ns * 16 + lr;
            float bias = b2[col];
            #pragma unroll
            for (int r = 0; r < 4; ++r)
                out[((size_t)b * D + mb + r) * HID + col] =
                    1.0f / (1.0f + expf(-(acc[ms][ns][r] + bias)));
        }
}

extern "C" void kernel_launch(void* const* d_in, const int* in_sizes, int n_in,
                              void* d_out, int out_size, void* d_ws, size_t ws_size,
                              hipStream_t stream) {
    const float* data     = (const float*)d_in[0];
    const float* emb      = (const float*)d_in[1];
    const float* lin_w    = (const float*)d_in[2];
    const float* att_i    = (const float*)d_in[3];
    const float* att_j    = (const float*)d_in[4];
    const float* att_em_i = (const float*)d_in[5];
    const float* att_em_j = (const float*)d_in[6];
    const float* gnn_bias = (const float*)d_in[7];
    const float* bn_gamma = (const float*)d_in[8];
    const float* bn_beta  = (const float*)d_in[9];
    const float* w1       = (const float*)d_in[10];
    const float* w2       = (const float*)d_in[11];
    const float* b2       = (const float*)d_in[12];
    float* out            = (float*)d_out;   // f32 outputs: [out | emb | topk_idx]

    float* ws       = (float*)d_ws;
    float* inv_norm = ws;                                  // 512 f32
    float* ei       = ws + 512;                            // 512 f32
    float* ej       = ws + 1024;                           // 512 f32
    int*   topk     = (int*)(ws + 1536);                   // 10240 i32
    float* s_i      = ws + 1536 + N * TOPK;                // 32768 f32
    float* s_j      = s_i + B * N;                         // 32768 f32
    short* S        = (short*)(ws + 77312);                // 24 MB region (16B aligned)
    short* Gt       = S;                                   // B*D*N bf16 = 8 MB
    short* out1     = S + (size_t)B * D * N;               // 8 MB
    short* xlb      = S + 2 * (size_t)B * D * N;           // 8 MB
    float* cosm     = (float*)S;                           // 1 MB, dead before attn2 writes Gt

    float* out_emb = out + (size_t)B * D * HID;
    float* out_idx = out_emb + (size_t)N * D;

    hipLaunchKernelGGL(k_norm,  dim3(N),              dim3(D),   0, stream, emb, att_em_i, att_em_j, inv_norm, ei, ej, out_emb);
    hipLaunchKernelGGL(k_cos,   dim3(N / 32, N / 32), dim3(256), 0, stream, emb, inv_norm, cosm);
    hipLaunchKernelGGL(k_sel,   dim3(N / 4),          dim3(256), 0, stream, cosm, topk, out_idx);
    hipLaunchKernelGGL(k_xl,    dim3(N / 64, B),      dim3(256), 0, stream, data, lin_w, att_i, att_j, ei, ej, xlb, s_i, s_j);
    hipLaunchKernelGGL(k_attn2, dim3(N / 16, B),      dim3(256), 0, stream, xlb, emb, topk, s_i, s_j, gnn_bias, bn_gamma, bn_beta, Gt);
    hipLaunchKernelGGL(k_gemm1, dim3(HID / 64, D / 64, B), dim3(256), 0, stream, Gt, w1, out1);
    hipLaunchKernelGGL(k_gemm2, dim3(HID / 64, D / 64, B), dim3(256), 0, stream, out1, w2, b2, out);
}